// Round 1
// baseline (3670.390 us; speedup 1.0000x reference)
//
#include <hip/hip_runtime.h>
#include <hip/hip_bf16.h>

typedef unsigned short ushort_t;
#define EPSQ 1e-8f

// ws layout (bytes):
//   wRTp  [9][64][132] fp32 : off 0        size 304128
//   pwRTp [64][132]    fp32 : off 304128   size 33792
//   Wb    [245760]     bf16 : off 337920   size 491520
//   u     [4096][384][8] f32: off 829440   size 50331648
// total ~51.2 MB

// ---------------- K0: weight prep ----------------
__global__ __launch_bounds__(256) void k0_prep(
    const float* __restrict__ w1, const float* __restrict__ pw,
    const float* __restrict__ Wf,
    float* __restrict__ wRTp, float* __restrict__ pwRTp,
    __hip_bfloat16* __restrict__ Wb)
{
  int i = blockIdx.x * 256 + threadIdx.x;   // grid 960*256 = 245760
  if (i < 76032) {
    int c  = i / 8448;
    int r  = i % 8448;
    int co = r / 132;
    int kl = r % 132;
    // kk = c*128 + kl ; k_conv = c ; ci = kl
    wRTp[i] = (co < 50 && kl < 128) ? w1[co*1152 + kl*9 + c] : 0.f;
  }
  if (i < 8448) {
    int co2 = i / 132;
    int j   = i % 132;
    int k   = j / 44;
    int pos = j % 44;
    pwRTp[i] = (pos < 42) ? pw[co2*126 + pos*3 + k] : 0.f;
  }
  Wb[i] = __float2bfloat16(Wf[i]);
}

// ---------------- K12: conv1 + relu + pconv + squash (one block per b) ----------------
__global__ __launch_bounds__(256) void k12_conv(
    const float* __restrict__ x, const float* __restrict__ b1,
    const float* __restrict__ b2,
    const float* __restrict__ wRTp, const float* __restrict__ pwRTp,
    float* __restrict__ u)
{
  __shared__ float wbuf[64*132];   // 33792 B, reused for pconv weights
  __shared__ float hr[50*44];      // conv1 out [ch][pos], pos padded 42->44 (cols 42,43 zero)
  __shared__ float pbuf[64*52];    // pconv out [co2][l2], l2 padded 48->52

  const int b    = blockIdx.x;
  const int tid  = threadIdx.x;
  const int wave = tid >> 6;
  const int lane = tid & 63;

  const float* xb = x + b*6400;

  // ---- phase A: conv1 GEMM. lane = co(64, 50 valid); wave covers l = wave+4i ----
  float acc[11];
#pragma unroll
  for (int i = 0; i < 11; ++i) acc[i] = 0.f;

  float4 pf[9];
  const float4* wg = (const float4*)wRTp;
#pragma unroll
  for (int j = 0; j < 9; ++j) {
    int idx = j*256 + tid;
    pf[j] = (idx < 2112) ? wg[idx] : make_float4(0.f,0.f,0.f,0.f);
  }

  for (int c = 0; c < 9; ++c) {
    __syncthreads();
#pragma unroll
    for (int j = 0; j < 9; ++j) {
      int idx = j*256 + tid;
      if (idx < 2112) ((float4*)wbuf)[idx] = pf[j];
    }
    __syncthreads();
    if (c < 8) {
#pragma unroll
      for (int j = 0; j < 9; ++j) {
        int idx = j*256 + tid;
        if (idx < 2112) pf[j] = wg[(c+1)*2112 + idx];
      }
    }
    for (int s = 0; s < 32; ++s) {
      float4 w4 = *(float4*)&wbuf[lane*132 + s*4];
#pragma unroll
      for (int i = 0; i < 11; ++i) {
        int l = wave + 4*i;
        if (l < 42) {
          // x window for row (b,l) is contiguous: addr = (l+k)*128+ci, kk=k*128+ci
          float4 x4 = *(const float4*)&xb[(l + c)*128 + s*4];
          acc[i] = fmaf(x4.x, w4.x, acc[i]);
          acc[i] = fmaf(x4.y, w4.y, acc[i]);
          acc[i] = fmaf(x4.z, w4.z, acc[i]);
          acc[i] = fmaf(x4.w, w4.w, acc[i]);
        }
      }
    }
  }

  __syncthreads();
  if (lane < 50) {
    float bias = b1[lane];
#pragma unroll
    for (int i = 0; i < 11; ++i) {
      int l = wave + 4*i;
      if (l < 42) hr[lane*44 + l] = fmaxf(acc[i] + bias, 0.f);
    }
    if (wave == 0) { hr[lane*44 + 42] = 0.f; hr[lane*44 + 43] = 0.f; }
  }
  __syncthreads();

  // ---- phase B: pconv GEMM. lane = co2(64); wave covers l2 = wave+4j (12 each) ----
  {
    const float4* pg = (const float4*)pwRTp;
#pragma unroll
    for (int j = 0; j < 9; ++j) {
      int idx = j*256 + tid;
      if (idx < 2112) ((float4*)wbuf)[idx] = pg[idx];
    }
  }
  __syncthreads();

  float pacc[12];
#pragma unroll
  for (int j = 0; j < 12; ++j) pacc[j] = 0.f;

  for (int k = 0; k < 3; ++k) {
    for (int tq = 0; tq < 11; ++tq) {
      float4 w4 = *(float4*)&wbuf[lane*132 + k*44 + tq*4];
#pragma unroll
      for (int j = 0; j < 12; ++j) {
        int l2 = wave + 4*j;
        float4 h4 = *(float4*)&hr[(l2 + k)*44 + tq*4];  // wave-uniform broadcast
        pacc[j] = fmaf(w4.x, h4.x, pacc[j]);
        pacc[j] = fmaf(w4.y, h4.y, pacc[j]);
        pacc[j] = fmaf(w4.z, h4.z, pacc[j]);
        pacc[j] = fmaf(w4.w, h4.w, pacc[j]);
      }
    }
  }
  {
    float bias = b2[lane];
#pragma unroll
    for (int j = 0; j < 12; ++j) {
      int l2 = wave + 4*j;
      pbuf[lane*52 + l2] = pacc[j] + bias;
    }
  }
  __syncthreads();

  // ---- phase C: squash over groups of 8 -> u[b][384][8] ----
  float* ub = u + b*3072;
  for (int rep = 0; rep < 2; ++rep) {
    int cap = tid + rep*256;
    if (cap < 384) {
      int co2 = cap / 6;
      int g   = cap % 6;
      float4 a0 = *(float4*)&pbuf[co2*52 + g*8];
      float4 a1 = *(float4*)&pbuf[co2*52 + g*8 + 4];
      float sq = a0.x*a0.x + a0.y*a0.y + a0.z*a0.z + a0.w*a0.w
               + a1.x*a1.x + a1.y*a1.y + a1.z*a1.z + a1.w*a1.w;
      float sc = sq / ((1.f + sq) * (sqrtf(sq) + EPSQ));
      float4 o0 = make_float4(a0.x*sc, a0.y*sc, a0.z*sc, a0.w*sc);
      float4 o1 = make_float4(a1.x*sc, a1.y*sc, a1.z*sc, a1.w*sc);
      *(float4*)&ub[cap*8]     = o0;
      *(float4*)&ub[cap*8 + 4] = o1;
    }
  }
}

// ---------------- K3: u_hat + dynamic routing (one block per b, thread = capsule c) ----------------
__global__ __launch_bounds__(384) void k3_route(
    const float* __restrict__ u, const ushort_t* __restrict__ Wu,
    float* __restrict__ out)
{
  // u_hat LDS layout [od 0..79][strip q 0..3][100 slots] + 4 extra per od row:
  // row stride 404 dwords -> bank = (20*od + 4*q + j) % 32 : <=2-way conflicts, 16B-aligned strips
  __shared__ float uh[80*404];     // 129280 B
  __shared__ float coc[5*404];     // 8080 B
  __shared__ float sv[80];
  __shared__ float ff[5];

  const int b = blockIdx.x;
  const int t = threadIdx.x;
  const int c = t;                  // capsule 0..383
  const int q = c / 96;
  const int jc = c % 96;
  const int cslot = q*100 + jc;

  // load u[b][c][0..7]
  const float* ug = u + b*3072 + c*8;
  float4 u0 = *(const float4*)ug;
  float4 u1 = *(const float4*)(ug + 4);

  // u_hat[o][c][d] = sum_i W[o][c][d][i]*u[c][i]  (W in bf16)
  float uhreg[80];
#pragma unroll
  for (int o = 0; o < 5; ++o) {
    const uint4* wp = (const uint4*)(Wu + (o*384 + c)*128);
#pragma unroll
    for (int d = 0; d < 16; ++d) {
      uint4 wv = wp[d];
      float w0 = __uint_as_float(wv.x << 16);
      float w1 = __uint_as_float(wv.x & 0xffff0000u);
      float w2 = __uint_as_float(wv.y << 16);
      float w3 = __uint_as_float(wv.y & 0xffff0000u);
      float w4 = __uint_as_float(wv.z << 16);
      float w5 = __uint_as_float(wv.z & 0xffff0000u);
      float w6 = __uint_as_float(wv.w << 16);
      float w7 = __uint_as_float(wv.w & 0xffff0000u);
      float s = w0*u0.x + w1*u0.y + w2*u0.z + w3*u0.w
              + w4*u1.x + w5*u1.y + w6*u1.z + w7*u1.w;
      uhreg[o*16 + d] = s;
      uh[(o*16 + d)*404 + cslot] = s;
    }
  }

  float lg[5] = {0.f,0.f,0.f,0.f,0.f};

  for (int it = 0; it < 3; ++it) {
    // softmax over o (local), write c_oc
    float m = fmaxf(fmaxf(fmaxf(lg[0],lg[1]),fmaxf(lg[2],lg[3])),lg[4]);
    float e[5]; float Z = 0.f;
#pragma unroll
    for (int o = 0; o < 5; ++o) { e[o] = __expf(lg[o]-m); Z += e[o]; }
    float inv = 1.f / Z;
#pragma unroll
    for (int o = 0; o < 5; ++o) coc[o*404 + cslot] = e[o]*inv;
    __syncthreads();

    // s-phase: (od,q)-threads sum c-strips, combine quarters via shfl
    if (t < 320) {
      int od = t >> 2, qq = t & 3, o = od >> 4;
      const float4* ca = (const float4*)&coc[o*404 + qq*100];
      const float4* ua = (const float4*)&uh[od*404 + qq*100];
      float sum = 0.f;
      for (int j = 0; j < 24; ++j) {
        float4 cv = ca[j]; float4 uv = ua[j];
        sum = fmaf(cv.x, uv.x, sum); sum = fmaf(cv.y, uv.y, sum);
        sum = fmaf(cv.z, uv.z, sum); sum = fmaf(cv.w, uv.w, sum);
      }
      sum += __shfl_xor(sum, 1);
      sum += __shfl_xor(sum, 2);
      if (qq == 0) sv[od] = sum;
    }
    __syncthreads();

    // squash factor per o
    if (t < 5) {
      float sq = 0.f;
#pragma unroll
      for (int d = 0; d < 16; ++d) { float v = sv[t*16+d]; sq = fmaf(v, v, sq); }
      ff[t] = sq / ((1.f + sq) * (sqrtf(sq) + EPSQ));
    }
    __syncthreads();

    if (it == 2) {
      if (t < 80) out[b*80 + t] = sv[t] * ff[t >> 4];
    } else {
      // logits update from register-resident u_hat
#pragma unroll
      for (int o = 0; o < 5; ++o) {
        float f = ff[o];
        float dv = 0.f;
#pragma unroll
        for (int d = 0; d < 16; ++d) dv = fmaf(uhreg[o*16+d], sv[o*16+d]*f, dv);
        lg[o] += dv;
      }
    }
  }
}

extern "C" void kernel_launch(void* const* d_in, const int* in_sizes, int n_in,
                              void* d_out, int out_size, void* d_ws, size_t ws_size,
                              hipStream_t stream) {
  const float* x  = (const float*)d_in[0];
  const float* w1 = (const float*)d_in[1];
  const float* b1 = (const float*)d_in[2];
  const float* pw = (const float*)d_in[3];
  const float* b2 = (const float*)d_in[4];
  const float* Wf = (const float*)d_in[5];
  float* out = (float*)d_out;
  char* ws = (char*)d_ws;

  float*          wRTp  = (float*)(ws);
  float*          pwRTp = (float*)(ws + 304128);
  __hip_bfloat16* Wb    = (__hip_bfloat16*)(ws + 337920);
  float*          u     = (float*)(ws + 829440);

  k0_prep<<<960, 256, 0, stream>>>(w1, pw, Wf, wRTp, pwRTp, Wb);
  k12_conv<<<4096, 256, 0, stream>>>(x, b1, b2, wRTp, pwRTp, u);
  k3_route<<<4096, 384, 0, stream>>>(u, (const ushort_t*)Wb, out);
}

// Round 2
// 1376.417 us; speedup vs baseline: 2.6666x; 2.6666x over previous
//
#include <hip/hip_runtime.h>
#include <hip/hip_bf16.h>

typedef unsigned short ushort_t;
#define EPSQ 1e-8f

// ws layout (bytes):
//   wRTp  [9][64][132] fp32 : off 0        size 304128
//   pwRTp [64][132]    fp32 : off 304128   size 33792
//   Wb    [245760]     bf16 : off 337920   size 491520
//   u     [4096][384][8] f32: off 829440   size 50331648

// ---------------- K0: weight prep ----------------
__global__ __launch_bounds__(256) void k0_prep(
    const float* __restrict__ w1, const float* __restrict__ pw,
    const float* __restrict__ Wf,
    float* __restrict__ wRTp, float* __restrict__ pwRTp,
    __hip_bfloat16* __restrict__ Wb)
{
  int i = blockIdx.x * 256 + threadIdx.x;   // grid 960*256 = 245760
  if (i < 76032) {
    int c  = i / 8448;
    int r  = i % 8448;
    int co = r / 132;
    int kl = r % 132;
    wRTp[i] = (co < 50 && kl < 128) ? w1[co*1152 + kl*9 + c] : 0.f;
  }
  if (i < 8448) {
    int co2 = i / 132;
    int j   = i % 132;
    int k   = j / 44;
    int pos = j % 44;
    pwRTp[i] = (pos < 42) ? pw[co2*126 + pos*3 + k] : 0.f;
  }
  Wb[i] = __float2bfloat16(Wf[i]);
}

// ---------------- K12: conv1 + relu + pconv + squash (one block per b) ----------------
// LDS plan (floats):
//   phase A: xbuf = smem[0 .. 7392)   (56 rows x 132, rows 50..55 zero pad)
//            wbuf = smem[7392 .. 15840)  (64 co x 132)
//   phase B: hr   = smem[0 .. 2200)   (50 x 44) — aliases dead xbuf
//            pbuf = smem[2200 .. 5528) (64 x 52)
//            wbuf reused for pconv weights
// total 15840 floats = 63360 B -> 2 blocks/CU
__global__ __launch_bounds__(256) void k12_conv(
    const float* __restrict__ x, const float* __restrict__ b1,
    const float* __restrict__ b2,
    const float* __restrict__ wRTp, const float* __restrict__ pwRTp,
    float* __restrict__ u)
{
  __shared__ float smem[15840];
  float* xbuf = smem;
  float* wbuf = smem + 7392;
  float* hr   = smem;
  float* pbuf = smem + 2200;

  const int b    = blockIdx.x;
  const int tid  = threadIdx.x;
  const int wave = tid >> 6;
  const int lane = tid & 63;
  const int lc   = lane & 15;     // co group: 4*lc .. 4*lc+3
  const int lsel = lane >> 4;     // 0..3
  const int lbase = wave + 4*lsel;  // 0..15, each value exactly once

  const float* xb = x + b*6400;

  // ---- stage x into LDS (stride 132), zero pad rows 50..55 ----
  {
    const float4* xg = (const float4*)xb;
    for (int j = tid; j < 1600; j += 256) {
      int p  = j >> 5;          // row (32 float4 per row)
      int q4 = j & 31;
      *(float4*)&xbuf[p*132 + q4*4] = xg[j];
    }
    for (int j = tid; j < 792; j += 256) xbuf[6600 + j] = 0.f;  // rows 50..55
  }

  // ---- phase A: conv1. thread tile = 4 co x 3 l ----
  float acc[12];
#pragma unroll
  for (int i = 0; i < 12; ++i) acc[i] = 0.f;

  float4 pf[9];
  const float4* wg = (const float4*)wRTp;
#pragma unroll
  for (int j = 0; j < 9; ++j) {
    int idx = j*256 + tid;
    pf[j] = (idx < 2112) ? wg[idx] : make_float4(0.f,0.f,0.f,0.f);
  }

  for (int c = 0; c < 9; ++c) {
    __syncthreads();
#pragma unroll
    for (int j = 0; j < 9; ++j) {
      int idx = j*256 + tid;
      if (idx < 2112) ((float4*)wbuf)[idx] = pf[j];
    }
    __syncthreads();
    if (c < 8) {
#pragma unroll
      for (int j = 0; j < 9; ++j) {
        int idx = j*256 + tid;
        if (idx < 2112) pf[j] = wg[(c+1)*2112 + idx];
      }
    }
    const float* wrow = &wbuf[lc*528];           // 4 co rows
    const float* xc   = &xbuf[(lbase + c)*132];  // rows lbase+c, +16, +32 (pad ok)
    for (int s = 0; s < 32; ++s) {
      int s4 = s*4;
      float4 w0 = *(const float4*)&wrow[s4];
      float4 w1 = *(const float4*)&wrow[132 + s4];
      float4 w2 = *(const float4*)&wrow[264 + s4];
      float4 w3 = *(const float4*)&wrow[396 + s4];
#pragma unroll
      for (int i = 0; i < 3; ++i) {
        float4 x4 = *(const float4*)&xc[i*2112 + s4];
        acc[i*4+0] = fmaf(x4.x, w0.x, acc[i*4+0]);
        acc[i*4+0] = fmaf(x4.y, w0.y, acc[i*4+0]);
        acc[i*4+0] = fmaf(x4.z, w0.z, acc[i*4+0]);
        acc[i*4+0] = fmaf(x4.w, w0.w, acc[i*4+0]);
        acc[i*4+1] = fmaf(x4.x, w1.x, acc[i*4+1]);
        acc[i*4+1] = fmaf(x4.y, w1.y, acc[i*4+1]);
        acc[i*4+1] = fmaf(x4.z, w1.z, acc[i*4+1]);
        acc[i*4+1] = fmaf(x4.w, w1.w, acc[i*4+1]);
        acc[i*4+2] = fmaf(x4.x, w2.x, acc[i*4+2]);
        acc[i*4+2] = fmaf(x4.y, w2.y, acc[i*4+2]);
        acc[i*4+2] = fmaf(x4.z, w2.z, acc[i*4+2]);
        acc[i*4+2] = fmaf(x4.w, w2.w, acc[i*4+2]);
        acc[i*4+3] = fmaf(x4.x, w3.x, acc[i*4+3]);
        acc[i*4+3] = fmaf(x4.y, w3.y, acc[i*4+3]);
        acc[i*4+3] = fmaf(x4.z, w3.z, acc[i*4+3]);
        acc[i*4+3] = fmaf(x4.w, w3.w, acc[i*4+3]);
      }
    }
  }

  __syncthreads();   // all xbuf reads done; safe to alias hr over it

  // ---- epilogue A: bias + relu -> hr[co*44 + l] ----
#pragma unroll
  for (int cc = 0; cc < 4; ++cc) {
    int co = 4*lc + cc;
    if (co < 50) {
      float bias = b1[co];
#pragma unroll
      for (int i = 0; i < 3; ++i) {
        int l = lbase + 16*i;
        if (l < 42) hr[co*44 + l] = fmaxf(acc[i*4+cc] + bias, 0.f);
      }
    }
  }
  if (tid < 50) { hr[tid*44 + 42] = 0.f; hr[tid*44 + 43] = 0.f; }

  // ---- stage pconv weights ----
  {
    const float4* pg = (const float4*)pwRTp;
#pragma unroll
    for (int j = 0; j < 9; ++j) {
      int idx = j*256 + tid;
      if (idx < 2112) ((float4*)wbuf)[idx] = pg[idx];
    }
  }
  __syncthreads();

  // ---- phase B: pconv. lane = co2; wave covers l2 = wave+4j ----
  float pacc[12];
#pragma unroll
  for (int j = 0; j < 12; ++j) pacc[j] = 0.f;

  for (int k = 0; k < 3; ++k) {
    for (int tq = 0; tq < 11; ++tq) {
      float4 w4 = *(const float4*)&wbuf[lane*132 + k*44 + tq*4];
#pragma unroll
      for (int j = 0; j < 12; ++j) {
        int l2 = wave + 4*j;
        float4 h4 = *(const float4*)&hr[(l2 + k)*44 + tq*4];  // wave-uniform broadcast
        pacc[j] = fmaf(w4.x, h4.x, pacc[j]);
        pacc[j] = fmaf(w4.y, h4.y, pacc[j]);
        pacc[j] = fmaf(w4.z, h4.z, pacc[j]);
        pacc[j] = fmaf(w4.w, h4.w, pacc[j]);
      }
    }
  }
  {
    float bias = b2[lane];
#pragma unroll
    for (int j = 0; j < 12; ++j) {
      int l2 = wave + 4*j;
      pbuf[lane*52 + l2] = pacc[j] + bias;
    }
  }
  __syncthreads();

  // ---- phase C: squash groups of 8 -> u[b][384][8] ----
  float* ub = u + b*3072;
  for (int rep = 0; rep < 2; ++rep) {
    int cap = tid + rep*256;
    if (cap < 384) {
      int co2 = cap / 6;
      int g   = cap % 6;
      float4 a0 = *(const float4*)&pbuf[co2*52 + g*8];
      float4 a1 = *(const float4*)&pbuf[co2*52 + g*8 + 4];
      float sq = a0.x*a0.x + a0.y*a0.y + a0.z*a0.z + a0.w*a0.w
               + a1.x*a1.x + a1.y*a1.y + a1.z*a1.z + a1.w*a1.w;
      float sc = sq / ((1.f + sq) * (sqrtf(sq) + EPSQ));
      *(float4*)&ub[cap*8]     = make_float4(a0.x*sc, a0.y*sc, a0.z*sc, a0.w*sc);
      *(float4*)&ub[cap*8 + 4] = make_float4(a1.x*sc, a1.y*sc, a1.z*sc, a1.w*sc);
    }
  }
}

// ---------------- K3: u_hat + dynamic routing (one block per b, thread = capsule c) ----------------
__global__ __launch_bounds__(384) void k3_route(
    const float* __restrict__ u, const ushort_t* __restrict__ Wu,
    float* __restrict__ out)
{
  __shared__ float uh[80*404];     // 129280 B
  __shared__ float coc[5*404];     // 8080 B
  __shared__ float sv[80];
  __shared__ float ff[5];

  const int b = blockIdx.x;
  const int t = threadIdx.x;
  const int c = t;
  const int q = c / 96;
  const int jc = c % 96;
  const int cslot = q*100 + jc;

  const float* ug = u + b*3072 + c*8;
  float4 u0 = *(const float4*)ug;
  float4 u1 = *(const float4*)(ug + 4);

  float uhreg[80];
#pragma unroll
  for (int o = 0; o < 5; ++o) {
    const uint4* wp = (const uint4*)(Wu + (o*384 + c)*128);
#pragma unroll
    for (int d = 0; d < 16; ++d) {
      uint4 wv = wp[d];
      float w0 = __uint_as_float(wv.x << 16);
      float w1 = __uint_as_float(wv.x & 0xffff0000u);
      float w2 = __uint_as_float(wv.y << 16);
      float w3 = __uint_as_float(wv.y & 0xffff0000u);
      float w4 = __uint_as_float(wv.z << 16);
      float w5 = __uint_as_float(wv.z & 0xffff0000u);
      float w6 = __uint_as_float(wv.w << 16);
      float w7 = __uint_as_float(wv.w & 0xffff0000u);
      float s = w0*u0.x + w1*u0.y + w2*u0.z + w3*u0.w
              + w4*u1.x + w5*u1.y + w6*u1.z + w7*u1.w;
      uhreg[o*16 + d] = s;
      uh[(o*16 + d)*404 + cslot] = s;
    }
  }

  float lg[5] = {0.f,0.f,0.f,0.f,0.f};

  for (int it = 0; it < 3; ++it) {
    float m = fmaxf(fmaxf(fmaxf(lg[0],lg[1]),fmaxf(lg[2],lg[3])),lg[4]);
    float e[5]; float Z = 0.f;
#pragma unroll
    for (int o = 0; o < 5; ++o) { e[o] = __expf(lg[o]-m); Z += e[o]; }
    float inv = 1.f / Z;
#pragma unroll
    for (int o = 0; o < 5; ++o) coc[o*404 + cslot] = e[o]*inv;
    __syncthreads();

    if (t < 320) {
      int od = t >> 2, qq = t & 3, o = od >> 4;
      const float4* ca = (const float4*)&coc[o*404 + qq*100];
      const float4* ua = (const float4*)&uh[od*404 + qq*100];
      float sum = 0.f;
      for (int j = 0; j < 24; ++j) {
        float4 cv = ca[j]; float4 uv = ua[j];
        sum = fmaf(cv.x, uv.x, sum); sum = fmaf(cv.y, uv.y, sum);
        sum = fmaf(cv.z, uv.z, sum); sum = fmaf(cv.w, uv.w, sum);
      }
      sum += __shfl_xor(sum, 1);
      sum += __shfl_xor(sum, 2);
      if (qq == 0) sv[od] = sum;
    }
    __syncthreads();

    if (t < 5) {
      float sq = 0.f;
#pragma unroll
      for (int d = 0; d < 16; ++d) { float v = sv[t*16+d]; sq = fmaf(v, v, sq); }
      ff[t] = sq / ((1.f + sq) * (sqrtf(sq) + EPSQ));
    }
    __syncthreads();

    if (it == 2) {
      if (t < 80) out[b*80 + t] = sv[t] * ff[t >> 4];
    } else {
#pragma unroll
      for (int o = 0; o < 5; ++o) {
        float f = ff[o];
        float dv = 0.f;
#pragma unroll
        for (int d = 0; d < 16; ++d) dv = fmaf(uhreg[o*16+d], sv[o*16+d]*f, dv);
        lg[o] += dv;
      }
    }
  }
}

extern "C" void kernel_launch(void* const* d_in, const int* in_sizes, int n_in,
                              void* d_out, int out_size, void* d_ws, size_t ws_size,
                              hipStream_t stream) {
  const float* x  = (const float*)d_in[0];
  const float* w1 = (const float*)d_in[1];
  const float* b1 = (const float*)d_in[2];
  const float* pw = (const float*)d_in[3];
  const float* b2 = (const float*)d_in[4];
  const float* Wf = (const float*)d_in[5];
  float* out = (float*)d_out;
  char* ws = (char*)d_ws;

  float*          wRTp  = (float*)(ws);
  float*          pwRTp = (float*)(ws + 304128);
  __hip_bfloat16* Wb    = (__hip_bfloat16*)(ws + 337920);
  float*          u     = (float*)(ws + 829440);

  k0_prep<<<960, 256, 0, stream>>>(w1, pw, Wf, wRTp, pwRTp, Wb);
  k12_conv<<<4096, 256, 0, stream>>>(x, b1, b2, wRTp, pwRTp, u);
  k3_route<<<4096, 384, 0, stream>>>(u, (const ushort_t*)Wb, out);
}

// Round 3
// 775.835 us; speedup vs baseline: 4.7309x; 1.7741x over previous
//
#include <hip/hip_runtime.h>
#include <hip/hip_bf16.h>

typedef unsigned short ushort_t;
typedef _Float16 half4_t __attribute__((ext_vector_type(4)));
typedef _Float16 half8_t __attribute__((ext_vector_type(8)));
typedef float f32x4 __attribute__((ext_vector_type(4)));
#define EPSQ 1e-8f

// ws layout (bytes):
//   wc16  [9][64][128] fp16 : off 0        size 147456   (conv1 weights, K-chunked)
//   pwRTp [64][132]    fp32 : off 147456   size 33792
//   Wb    [245760]     bf16 : off 181248   size 491520
//   u     [4096][384][8] f32: off 672768   size 50331648

// ---------------- K0: weight prep ----------------
__global__ __launch_bounds__(256) void k0_prep(
    const float* __restrict__ w1, const float* __restrict__ pw,
    const float* __restrict__ Wf,
    _Float16* __restrict__ wc16, float* __restrict__ pwRTp,
    __hip_bfloat16* __restrict__ Wb)
{
  int i = blockIdx.x * 256 + threadIdx.x;   // grid 960*256 = 245760
  if (i < 73728) {
    int c  = i / 8192;
    int r  = i % 8192;
    int co = r >> 7;
    int k  = r & 127;
    // kk = c*128 + k ; conv tap c, input channel k
    wc16[i] = (co < 50) ? (_Float16)w1[co*1152 + k*9 + c] : (_Float16)0.f;
  }
  if (i < 8448) {
    int co2 = i / 132;
    int j   = i % 132;
    int k   = j / 44;
    int pos = j % 44;
    pwRTp[i] = (pos < 42) ? pw[co2*126 + pos*3 + k] : 0.f;
  }
  Wb[i] = __float2bfloat16(Wf[i]);
}

// ---------------- K12: MFMA conv1 + relu + pconv + squash (3 b per block) ----------------
// LDS (floats, total 18904 = 75616 B -> 2 blocks/CU):
//   MFMA phase: xh   = halves[0..20400)       [3][50][136] fp16 (row pad 128->136)
//               Bbuf = halves[20400..37808)   2 x [64][136] fp16 (double buffer)
//   pconv phase (aliased): hbuf = floats[0..6600)      [3][50*44]
//                          pbuf = floats[6600..9928)   [64*52]
//                          pw   = floats[10200..18648) [64*132]
__global__ __launch_bounds__(256) void k12_mfma(
    const float* __restrict__ x, const float* __restrict__ b1,
    const float* __restrict__ b2, const _Float16* __restrict__ wc16,
    const float* __restrict__ pwRTp, float* __restrict__ u)
{
  __shared__ float smem[18904];
  _Float16* xh   = (_Float16*)smem;
  float*    hbuf = smem;
  float*    pbuf = smem + 6600;
  float*    pw   = smem + 10200;

  const int tid   = threadIdx.x;
  const int w     = tid >> 6;
  const int lane  = tid & 63;
  const int lc    = lane & 15;
  const int qd    = lane >> 4;
  const int gbase = blockIdx.x * 3;

  // ---- stage x: fp32 -> fp16 into padded rows ----
  for (int j = tid; j < 4800; j += 256) {
    int g = j / 1600, r = j - g*1600;
    int p = r >> 5, q = r & 31;
    int bb = gbase + g; if (bb > 4095) bb = 4095;
    float4 v = *(const float4*)(x + bb*6400 + p*128 + q*4);
    half4_t hv = {(_Float16)v.x, (_Float16)v.y, (_Float16)v.z, (_Float16)v.w};
    *(half4_t*)(xh + g*6800 + p*136 + q*4) = hv;
  }
  // ---- stage w chunk 0 into Bbuf0 ----
  {
    const uint4* wg = (const uint4*)wc16;
    uint4* dst = (uint4*)(xh + 20400);
#pragma unroll
    for (int it = 0; it < 4; ++it) {
      int f = it*256 + tid;
      dst[(f >> 4)*17 + (f & 15)] = wg[f];
    }
  }

  // A-fragment row base pointers (A[m = lane&15][k = qd*8 + j])
  const _Float16* abase[2];
#pragma unroll
  for (int tm = 0; tm < 2; ++tm) {
    int m = 32*w + 16*tm + lc;
    if (m > 125) m = 125;            // pad rows clamp (results discarded)
    int g = m / 42, l = m - g*42;
    abase[tm] = xh + g*6800 + l*136 + qd*8;   // window row p = l + c -> +c*136
  }

  f32x4 acc[2][4];
#pragma unroll
  for (int tm = 0; tm < 2; ++tm)
#pragma unroll
    for (int tn = 0; tn < 4; ++tn)
      acc[tm][tn] = (f32x4){0.f, 0.f, 0.f, 0.f};

  __syncthreads();

  uint4 pf[4];
  for (int c = 0; c < 9; ++c) {
    if (c < 8) {
      const uint4* wg = (const uint4*)wc16 + (c + 1)*1024;
#pragma unroll
      for (int it = 0; it < 4; ++it) pf[it] = wg[it*256 + tid];
    }
    const _Float16* Bb = xh + 20400 + (c & 1)*8704;
    const _Float16* a0 = abase[0] + c*136;
    const _Float16* a1 = abase[1] + c*136;
#pragma unroll
    for (int kk = 0; kk < 128; kk += 32) {
      half8_t av0 = *(const half8_t*)(a0 + kk);
      half8_t av1 = *(const half8_t*)(a1 + kk);
#pragma unroll
      for (int tn = 0; tn < 4; ++tn) {
        half8_t bv = *(const half8_t*)(Bb + (16*tn + lc)*136 + qd*8 + kk);
        acc[0][tn] = __builtin_amdgcn_mfma_f32_16x16x32_f16(av0, bv, acc[0][tn], 0, 0, 0);
        acc[1][tn] = __builtin_amdgcn_mfma_f32_16x16x32_f16(av1, bv, acc[1][tn], 0, 0, 0);
      }
    }
    __syncthreads();
    if (c < 8) {
      uint4* dst = (uint4*)(xh + 20400 + ((c + 1) & 1)*8704);
#pragma unroll
      for (int it = 0; it < 4; ++it) {
        int f = it*256 + tid;
        dst[(f >> 4)*17 + (f & 15)] = pf[it];
      }
      __syncthreads();
    }
  }
  // all xh / Bbuf reads complete past the final barrier -> safe to alias

  // ---- epilogue: bias + relu -> hbuf[g][co*44 + l]  (C/D: col=lane&15, row=qd*4+r) ----
#pragma unroll
  for (int tm = 0; tm < 2; ++tm) {
    int mb = 32*w + 16*tm + 4*qd;
#pragma unroll
    for (int tn = 0; tn < 4; ++tn) {
      int co = 16*tn + lc;
      if (co < 50) {
        float bias = b1[co];
#pragma unroll
        for (int r = 0; r < 4; ++r) {
          int m = mb + r;
          if (m < 126) {
            int g = m / 42, l = m - g*42;
            hbuf[g*2200 + co*44 + l] = fmaxf(acc[tm][tn][r] + bias, 0.f);
          }
        }
      }
    }
  }
  // zero pad cols l=42,43
  for (int j = tid; j < 300; j += 256) {
    int g = j / 100, r = j - g*100;
    hbuf[g*2200 + (r >> 1)*44 + 42 + (r & 1)] = 0.f;
  }
  // stage pconv weights (aliases dead Bbuf region)
  {
    const float4* pg = (const float4*)pwRTp;
#pragma unroll
    for (int it = 0; it < 9; ++it) {
      int idx = it*256 + tid;
      if (idx < 2112) ((float4*)pw)[idx] = pg[idx];
    }
  }
  __syncthreads();

  // ---- pconv + squash per b ----
  for (int g = 0; g < 3; ++g) {
    const float* hg = hbuf + g*2200;
    float pacc[12];
#pragma unroll
    for (int j = 0; j < 12; ++j) pacc[j] = 0.f;

    for (int k = 0; k < 3; ++k) {
      for (int tq = 0; tq < 11; ++tq) {
        float4 w4 = *(const float4*)&pw[lane*132 + k*44 + tq*4];
#pragma unroll
        for (int j = 0; j < 12; ++j) {
          int l2 = w + 4*j;
          float4 h4 = *(const float4*)&hg[(l2 + k)*44 + tq*4];  // wave-uniform broadcast
          pacc[j] = fmaf(w4.x, h4.x, pacc[j]);
          pacc[j] = fmaf(w4.y, h4.y, pacc[j]);
          pacc[j] = fmaf(w4.z, h4.z, pacc[j]);
          pacc[j] = fmaf(w4.w, h4.w, pacc[j]);
        }
      }
    }
    {
      float bias2 = b2[lane];
#pragma unroll
      for (int j = 0; j < 12; ++j) pbuf[lane*52 + (w + 4*j)] = pacc[j] + bias2;
    }
    __syncthreads();

    int bb = gbase + g;
    if (bb < 4096) {
      float* ub = u + bb*3072;
      for (int rep = 0; rep < 2; ++rep) {
        int cap = tid + rep*256;
        if (cap < 384) {
          int co2 = cap / 6;
          int gg  = cap % 6;
          float4 a0 = *(const float4*)&pbuf[co2*52 + gg*8];
          float4 a1 = *(const float4*)&pbuf[co2*52 + gg*8 + 4];
          float sq = a0.x*a0.x + a0.y*a0.y + a0.z*a0.z + a0.w*a0.w
                   + a1.x*a1.x + a1.y*a1.y + a1.z*a1.z + a1.w*a1.w;
          float sc = sq / ((1.f + sq) * (sqrtf(sq) + EPSQ));
          *(float4*)&ub[cap*8]     = make_float4(a0.x*sc, a0.y*sc, a0.z*sc, a0.w*sc);
          *(float4*)&ub[cap*8 + 4] = make_float4(a1.x*sc, a1.y*sc, a1.z*sc, a1.w*sc);
        }
      }
    }
    __syncthreads();
  }
}

// ---------------- K3: u_hat + dynamic routing (one block per b, thread = capsule c) ----------------
__global__ __launch_bounds__(384) void k3_route(
    const float* __restrict__ u, const ushort_t* __restrict__ Wu,
    float* __restrict__ out)
{
  __shared__ float uh[80*404];     // 129280 B
  __shared__ float coc[5*404];     // 8080 B
  __shared__ float sv[80];
  __shared__ float ff[5];

  const int b = blockIdx.x;
  const int t = threadIdx.x;
  const int c = t;
  const int q = c / 96;
  const int jc = c % 96;
  const int cslot = q*100 + jc;

  const float* ug = u + b*3072 + c*8;
  float4 u0 = *(const float4*)ug;
  float4 u1 = *(const float4*)(ug + 4);

  float uhreg[80];
#pragma unroll
  for (int o = 0; o < 5; ++o) {
    const uint4* wp = (const uint4*)(Wu + (o*384 + c)*128);
#pragma unroll
    for (int d = 0; d < 16; ++d) {
      uint4 wv = wp[d];
      float w0 = __uint_as_float(wv.x << 16);
      float w1 = __uint_as_float(wv.x & 0xffff0000u);
      float w2 = __uint_as_float(wv.y << 16);
      float w3 = __uint_as_float(wv.y & 0xffff0000u);
      float w4 = __uint_as_float(wv.z << 16);
      float w5 = __uint_as_float(wv.z & 0xffff0000u);
      float w6 = __uint_as_float(wv.w << 16);
      float w7 = __uint_as_float(wv.w & 0xffff0000u);
      float s = w0*u0.x + w1*u0.y + w2*u0.z + w3*u0.w
              + w4*u1.x + w5*u1.y + w6*u1.z + w7*u1.w;
      uhreg[o*16 + d] = s;
      uh[(o*16 + d)*404 + cslot] = s;
    }
  }

  float lg[5] = {0.f,0.f,0.f,0.f,0.f};

  for (int it = 0; it < 3; ++it) {
    float m = fmaxf(fmaxf(fmaxf(lg[0],lg[1]),fmaxf(lg[2],lg[3])),lg[4]);
    float e[5]; float Z = 0.f;
#pragma unroll
    for (int o = 0; o < 5; ++o) { e[o] = __expf(lg[o]-m); Z += e[o]; }
    float inv = 1.f / Z;
#pragma unroll
    for (int o = 0; o < 5; ++o) coc[o*404 + cslot] = e[o]*inv;
    __syncthreads();

    if (t < 320) {
      int od = t >> 2, qq = t & 3, o = od >> 4;
      const float4* ca = (const float4*)&coc[o*404 + qq*100];
      const float4* ua = (const float4*)&uh[od*404 + qq*100];
      float sum = 0.f;
      for (int j = 0; j < 24; ++j) {
        float4 cv = ca[j]; float4 uv = ua[j];
        sum = fmaf(cv.x, uv.x, sum); sum = fmaf(cv.y, uv.y, sum);
        sum = fmaf(cv.z, uv.z, sum); sum = fmaf(cv.w, uv.w, sum);
      }
      sum += __shfl_xor(sum, 1);
      sum += __shfl_xor(sum, 2);
      if (qq == 0) sv[od] = sum;
    }
    __syncthreads();

    if (t < 5) {
      float sq = 0.f;
#pragma unroll
      for (int d = 0; d < 16; ++d) { float v = sv[t*16+d]; sq = fmaf(v, v, sq); }
      ff[t] = sq / ((1.f + sq) * (sqrtf(sq) + EPSQ));
    }
    __syncthreads();

    if (it == 2) {
      if (t < 80) out[b*80 + t] = sv[t] * ff[t >> 4];
    } else {
#pragma unroll
      for (int o = 0; o < 5; ++o) {
        float f = ff[o];
        float dv = 0.f;
#pragma unroll
        for (int d = 0; d < 16; ++d) dv = fmaf(uhreg[o*16+d], sv[o*16+d]*f, dv);
        lg[o] += dv;
      }
    }
  }
}

extern "C" void kernel_launch(void* const* d_in, const int* in_sizes, int n_in,
                              void* d_out, int out_size, void* d_ws, size_t ws_size,
                              hipStream_t stream) {
  const float* x  = (const float*)d_in[0];
  const float* w1 = (const float*)d_in[1];
  const float* b1 = (const float*)d_in[2];
  const float* pw = (const float*)d_in[3];
  const float* b2 = (const float*)d_in[4];
  const float* Wf = (const float*)d_in[5];
  float* out = (float*)d_out;
  char* ws = (char*)d_ws;

  _Float16*       wc16  = (_Float16*)(ws);
  float*          pwRTp = (float*)(ws + 147456);
  __hip_bfloat16* Wb    = (__hip_bfloat16*)(ws + 181248);
  float*          u     = (float*)(ws + 672768);

  k0_prep<<<960, 256, 0, stream>>>(w1, pw, Wf, wc16, pwRTp, Wb);
  k12_mfma<<<1366, 256, 0, stream>>>(x, b1, b2, wc16, pwRTp, u);
  k3_route<<<4096, 384, 0, stream>>>(u, (const ushort_t*)Wb, out);
}

// Round 5
// 584.194 us; speedup vs baseline: 6.2828x; 1.3280x over previous
//
#include <hip/hip_runtime.h>
#include <hip/hip_bf16.h>

typedef unsigned short ushort_t;
typedef _Float16 half4_t __attribute__((ext_vector_type(4)));
typedef _Float16 half8_t __attribute__((ext_vector_type(8)));
typedef float f32x4 __attribute__((ext_vector_type(4)));
#define EPSQ 1e-8f

// ws layout (bytes):
//   wc16  [9][64][128] fp16 : off 0        size 147456   (conv1 weights, K-chunked)
//   pwB16 [64][160]    fp16 : off 147456   size 20480    (pconv weights, kk=k*48+ci, zero-padded)
//   Wb    [245760]     bf16 : off 167936   size 491520
//   u     [4096][384][8] f32: off 659456   size 50331648

// ---------------- K0: weight prep ----------------
__global__ __launch_bounds__(256) void k0_prep(
    const float* __restrict__ w1, const float* __restrict__ pw,
    const float* __restrict__ Wf,
    _Float16* __restrict__ wc16, _Float16* __restrict__ pwB16,
    __hip_bfloat16* __restrict__ Wb)
{
  int i = blockIdx.x * 256 + threadIdx.x;   // grid 960*256 = 245760
  if (i < 73728) {
    int c  = i / 8192;
    int r  = i % 8192;
    int co = r >> 7;
    int k  = r & 127;
    wc16[i] = (co < 50) ? (_Float16)w1[co*1152 + k*9 + c] : (_Float16)0.f;
  }
  if (i < 10240) {
    int co2 = i / 160, kk = i % 160;
    int k = kk / 48, ci = kk % 48;
    float v = (k < 3 && ci < 42) ? pw[co2*126 + ci*3 + k] : 0.f;
    pwB16[i] = (_Float16)v;
  }
  Wb[i] = __float2bfloat16(Wf[i]);
}

// ---------------- K12: MFMA conv1 + relu + MFMA pconv + squash (3 b per block) ----------------
// LDS (dwords, total 19728 = 78912 B -> 2 blocks/CU):
//   phase A: xh   = halves[0..20400)     [3][50][136] fp16
//            Bbuf = halves[20400..37808) 2 x [64][136] fp16 double buffer
//   phase P (aliased): hr16 = halves[0..8736)     [3][52][56] fp16 (rows=conv1 chan, cols=pos, zero-pad)
//                      pB   = halves[8736..19488) [64][168] fp16 (160 valid)
//                      pbuf = dwords[9744..19728) [3][64][52] fp32
__global__ __launch_bounds__(256) void k12_mfma(
    const float* __restrict__ x, const float* __restrict__ b1,
    const float* __restrict__ b2, const _Float16* __restrict__ wc16,
    const _Float16* __restrict__ pwB16, float* __restrict__ u)
{
  __shared__ float smem[19728];
  _Float16* xh   = (_Float16*)smem;
  _Float16* hr16 = (_Float16*)smem;
  _Float16* pB   = (_Float16*)smem + 8736;
  float*    pbuf = smem + 9744;

  const int tid   = threadIdx.x;
  const int w     = tid >> 6;
  const int lane  = tid & 63;
  const int lc    = lane & 15;
  const int qd    = lane >> 4;
  const int gbase = blockIdx.x * 3;

  // ---- stage x: fp32 -> fp16 into padded rows ----
  for (int j = tid; j < 4800; j += 256) {
    int g = j / 1600, r = j - g*1600;
    int p = r >> 5, q = r & 31;
    int bb = gbase + g; if (bb > 4095) bb = 4095;
    float4 v = *(const float4*)(x + bb*6400 + p*128 + q*4);
    half4_t hv = {(_Float16)v.x, (_Float16)v.y, (_Float16)v.z, (_Float16)v.w};
    *(half4_t*)(xh + g*6800 + p*136 + q*4) = hv;
  }
  // ---- stage w chunk 0 into Bbuf0 ----
  {
    const uint4* wg = (const uint4*)wc16;
    uint4* dst = (uint4*)(xh + 20400);
#pragma unroll
    for (int it = 0; it < 4; ++it) {
      int f = it*256 + tid;
      dst[(f >> 4)*17 + (f & 15)] = wg[f];
    }
  }

  const _Float16* abase[2];
#pragma unroll
  for (int tm = 0; tm < 2; ++tm) {
    int m = 32*w + 16*tm + lc;
    if (m > 125) m = 125;
    int g = m / 42, l = m - g*42;
    abase[tm] = xh + g*6800 + l*136 + qd*8;
  }

  f32x4 acc[2][4];
#pragma unroll
  for (int tm = 0; tm < 2; ++tm)
#pragma unroll
    for (int tn = 0; tn < 4; ++tn)
      acc[tm][tn] = (f32x4){0.f, 0.f, 0.f, 0.f};

  __syncthreads();

  uint4 pf[4];
  for (int c = 0; c < 9; ++c) {
    if (c < 8) {
      const uint4* wg = (const uint4*)wc16 + (c + 1)*1024;
#pragma unroll
      for (int it = 0; it < 4; ++it) pf[it] = wg[it*256 + tid];
    }
    const _Float16* Bb = xh + 20400 + (c & 1)*8704;
    const _Float16* a0 = abase[0] + c*136;
    const _Float16* a1 = abase[1] + c*136;
#pragma unroll
    for (int kk = 0; kk < 128; kk += 32) {
      half8_t av0 = *(const half8_t*)(a0 + kk);
      half8_t av1 = *(const half8_t*)(a1 + kk);
#pragma unroll
      for (int tn = 0; tn < 4; ++tn) {
        half8_t bv = *(const half8_t*)(Bb + (16*tn + lc)*136 + qd*8 + kk);
        acc[0][tn] = __builtin_amdgcn_mfma_f32_16x16x32_f16(av0, bv, acc[0][tn], 0, 0, 0);
        acc[1][tn] = __builtin_amdgcn_mfma_f32_16x16x32_f16(av1, bv, acc[1][tn], 0, 0, 0);
      }
    }
    __syncthreads();
    if (c < 8) {
      uint4* dst = (uint4*)(xh + 20400 + ((c + 1) & 1)*8704);
#pragma unroll
      for (int it = 0; it < 4; ++it) {
        int f = it*256 + tid;
        dst[(f >> 4)*17 + (f & 15)] = pf[it];
      }
      __syncthreads();
    }
  }
  // all xh/Bbuf reads done -> alias phase-P buffers

  // ---- zero hr16 and stage pconv weights ----
  for (int j = tid; j < 4368; j += 256) smem[j] = 0.f;
  {
    const uint4* pg = (const uint4*)pwB16;
    uint4* dst = (uint4*)pB;
    for (int f = tid; f < 1280; f += 256) {    // FIX: was 640 — rows 32..63 were uninitialized
      int row = f / 20, cc = f - row*20;
      dst[row*21 + cc] = pg[f];
    }
  }
  __syncthreads();

  // ---- conv1 epilogue: bias+relu -> hr16[g][co][l] fp16 ----
#pragma unroll
  for (int tm = 0; tm < 2; ++tm) {
    int mb = 32*w + 16*tm + 4*qd;
#pragma unroll
    for (int tn = 0; tn < 4; ++tn) {
      int co = 16*tn + lc;
      if (co < 50) {
        float bias = b1[co];
#pragma unroll
        for (int r = 0; r < 4; ++r) {
          int m = mb + r;
          if (m < 126) {
            int g = m / 42, l = m - g*42;
            hr16[g*2912 + co*56 + l] = (_Float16)fmaxf(acc[tm][tn][r] + bias, 0.f);
          }
        }
      }
    }
  }
  __syncthreads();

  // ---- pconv MFMA: M=144 (9 tiles of 16), N=64, K=160 ----
  f32x4 acc2[3][4];
#pragma unroll
  for (int tm = 0; tm < 3; ++tm)
#pragma unroll
    for (int tn = 0; tn < 4; ++tn)
      acc2[tm][tn] = (f32x4){0.f, 0.f, 0.f, 0.f};

#pragma unroll
  for (int kc = 0; kc < 5; ++kc) {
    int kk0 = kc*32 + qd*8;
    int k   = (kk0 >= 144) ? 3 : (kk0 >= 96) ? 2 : (kk0 >= 48) ? 1 : 0;
    int ci0 = kk0 - k*48;
    half8_t bv[4];
#pragma unroll
    for (int tn = 0; tn < 4; ++tn)
      bv[tn] = *(const half8_t*)(pB + (16*tn + lc)*168 + kk0);
#pragma unroll
    for (int tm = 0; tm < 3; ++tm) {
      int T = w + 4*tm; int Tc = (T < 9) ? T : 8;
      int g = Tc/3, l2 = (Tc - g*3)*16 + lc;
      half8_t av = *(const half8_t*)(hr16 + g*2912 + (l2 + k)*56 + ci0);
#pragma unroll
      for (int tn = 0; tn < 4; ++tn)
        acc2[tm][tn] = __builtin_amdgcn_mfma_f32_16x16x32_f16(av, bv[tn], acc2[tm][tn], 0, 0, 0);
    }
  }

  // ---- pconv epilogue -> pbuf[g][co2][l2] ----
#pragma unroll
  for (int tm = 0; tm < 3; ++tm) {
    int T = w + 4*tm;
    if (T < 9) {
      int g = T/3, l2b = (T - g*3)*16;
#pragma unroll
      for (int tn = 0; tn < 4; ++tn) {
        int co2 = 16*tn + lc;
        float bias2 = b2[co2];
#pragma unroll
        for (int r = 0; r < 4; ++r) {
          int l2 = l2b + 4*qd + r;
          pbuf[g*3328 + co2*52 + l2] = acc2[tm][tn][r] + bias2;
        }
      }
    }
  }
  __syncthreads();

  // ---- squash all 3 g -> u ----
  for (int idx = tid; idx < 1152; idx += 256) {
    int g = idx / 384, cap = idx - g*384;
    int bb = gbase + g;
    if (bb < 4096) {
      int co2 = cap / 6, gg = cap - co2*6;
      const float* pp = pbuf + g*3328 + co2*52 + gg*8;
      float4 a0 = *(const float4*)pp;
      float4 a1 = *(const float4*)(pp + 4);
      float sq = a0.x*a0.x + a0.y*a0.y + a0.z*a0.z + a0.w*a0.w
               + a1.x*a1.x + a1.y*a1.y + a1.z*a1.z + a1.w*a1.w;
      float sc = sq / ((1.f + sq) * (sqrtf(sq) + EPSQ));
      float* ub = u + bb*3072 + cap*8;
      *(float4*)ub       = make_float4(a0.x*sc, a0.y*sc, a0.z*sc, a0.w*sc);
      *(float4*)(ub + 4) = make_float4(a1.x*sc, a1.y*sc, a1.z*sc, a1.w*sc);
    }
  }
}

// ---------------- K3: u_hat + dynamic routing (one block per b, thread = capsule c) ----------------
// uh in LDS as bf16: [od 0..79][4 strips x 104 halves] row stride 416 halves.
// LDS ~75 KB -> 2 blocks/CU.
__global__ __launch_bounds__(384) void k3_route(
    const float* __restrict__ u, const ushort_t* __restrict__ Wu,
    float* __restrict__ out)
{
  __shared__ __align__(16) ushort_t uh16[80*416];  // 66560 B
  __shared__ __align__(16) float coc[5*404];       // 8080 B
  __shared__ float sv[80];
  __shared__ float ff[5];

  const int b = blockIdx.x;
  const int t = threadIdx.x;
  const int q  = t / 96;
  const int jc = t - q*96;
  const int ch = q*104 + jc;   // uh16 slot (halves)
  const int cf = q*100 + jc;   // coc slot (dwords)

  const float* ug = u + b*3072 + t*8;
  float4 u0 = *(const float4*)ug;
  float4 u1 = *(const float4*)(ug + 4);

  float uhreg[80];
#pragma unroll
  for (int o = 0; o < 5; ++o) {
    const uint4* wp = (const uint4*)(Wu + (o*384 + t)*128);
#pragma unroll
    for (int d = 0; d < 16; ++d) {
      uint4 wv = wp[d];
      float w0 = __uint_as_float(wv.x << 16);
      float w1 = __uint_as_float(wv.x & 0xffff0000u);
      float w2 = __uint_as_float(wv.y << 16);
      float w3 = __uint_as_float(wv.y & 0xffff0000u);
      float w4 = __uint_as_float(wv.z << 16);
      float w5 = __uint_as_float(wv.z & 0xffff0000u);
      float w6 = __uint_as_float(wv.w << 16);
      float w7 = __uint_as_float(wv.w & 0xffff0000u);
      float s = w0*u0.x + w1*u0.y + w2*u0.z + w3*u0.w
              + w4*u1.x + w5*u1.y + w6*u1.z + w7*u1.w;
      uhreg[o*16 + d] = s;
      __hip_bfloat16 hb = __float2bfloat16(s);
      uh16[(o*16 + d)*416 + ch] = *(ushort_t*)&hb;
    }
  }

  float lg[5] = {0.f,0.f,0.f,0.f,0.f};

  for (int it = 0; it < 3; ++it) {
    float m = fmaxf(fmaxf(fmaxf(lg[0],lg[1]),fmaxf(lg[2],lg[3])),lg[4]);
    float e[5]; float Z = 0.f;
#pragma unroll
    for (int o = 0; o < 5; ++o) { e[o] = __expf(lg[o]-m); Z += e[o]; }
    float inv = 1.f / Z;
#pragma unroll
    for (int o = 0; o < 5; ++o) coc[o*404 + cf] = e[o]*inv;
    __syncthreads();

    // s-phase: thread (od,qq) dots one 96-c strip; combine quarters via shfl
    if (t < 320) {
      int od = t >> 2, qq = t & 3, o = od >> 4;
      const float4* ca = (const float4*)&coc[o*404 + qq*100];
      const uint4*  ua = (const uint4*)&uh16[od*416 + qq*104];
      float sum = 0.f;
#pragma unroll 4
      for (int j = 0; j < 12; ++j) {
        uint4 uv = ua[j];
        float4 c0 = ca[2*j], c1 = ca[2*j + 1];
        sum = fmaf(c0.x, __uint_as_float(uv.x << 16),          sum);
        sum = fmaf(c0.y, __uint_as_float(uv.x & 0xffff0000u),  sum);
        sum = fmaf(c0.z, __uint_as_float(uv.y << 16),          sum);
        sum = fmaf(c0.w, __uint_as_float(uv.y & 0xffff0000u),  sum);
        sum = fmaf(c1.x, __uint_as_float(uv.z << 16),          sum);
        sum = fmaf(c1.y, __uint_as_float(uv.z & 0xffff0000u),  sum);
        sum = fmaf(c1.z, __uint_as_float(uv.w << 16),          sum);
        sum = fmaf(c1.w, __uint_as_float(uv.w & 0xffff0000u),  sum);
      }
      sum += __shfl_xor(sum, 1);
      sum += __shfl_xor(sum, 2);
      if (qq == 0) sv[od] = sum;
    }
    __syncthreads();

    if (t < 5) {
      float sq = 0.f;
#pragma unroll
      for (int d = 0; d < 16; ++d) { float v = sv[t*16+d]; sq = fmaf(v, v, sq); }
      ff[t] = sq / ((1.f + sq) * (sqrtf(sq) + EPSQ));
    }
    __syncthreads();

    if (it == 2) {
      if (t < 80) out[b*80 + t] = sv[t] * ff[t >> 4];
    } else {
#pragma unroll
      for (int o = 0; o < 5; ++o) {
        float f = ff[o];
        float dv = 0.f;
#pragma unroll
        for (int d = 0; d < 16; ++d) dv = fmaf(uhreg[o*16+d], sv[o*16+d]*f, dv);
        lg[o] += dv;
      }
    }
  }
}

extern "C" void kernel_launch(void* const* d_in, const int* in_sizes, int n_in,
                              void* d_out, int out_size, void* d_ws, size_t ws_size,
                              hipStream_t stream) {
  const float* x  = (const float*)d_in[0];
  const float* w1 = (const float*)d_in[1];
  const float* b1 = (const float*)d_in[2];
  const float* pw = (const float*)d_in[3];
  const float* b2 = (const float*)d_in[4];
  const float* Wf = (const float*)d_in[5];
  float* out = (float*)d_out;
  char* ws = (char*)d_ws;

  _Float16*       wc16  = (_Float16*)(ws);
  _Float16*       pwB16 = (_Float16*)(ws + 147456);
  __hip_bfloat16* Wb    = (__hip_bfloat16*)(ws + 167936);
  float*          u     = (float*)(ws + 659456);

  k0_prep<<<960, 256, 0, stream>>>(w1, pw, Wf, wc16, pwB16, Wb);
  k12_mfma<<<1366, 256, 0, stream>>>(x, b1, b2, wc16, pwB16, u);
  k3_route<<<4096, 384, 0, stream>>>(u, (const ushort_t*)Wb, out);
}

// Round 6
// 449.576 us; speedup vs baseline: 8.1641x; 1.2994x over previous
//
#include <hip/hip_runtime.h>
#include <hip/hip_bf16.h>

typedef unsigned short ushort_t;
typedef _Float16 h2 __attribute__((ext_vector_type(2)));
typedef _Float16 half4_t __attribute__((ext_vector_type(4)));
typedef _Float16 half8_t __attribute__((ext_vector_type(8)));
typedef float f32x4 __attribute__((ext_vector_type(4)));
#define EPSQ 1e-8f

__device__ __forceinline__ float fdot2f(h2 a, h2 b, float c) {
#if __has_builtin(__builtin_amdgcn_fdot2)
  return __builtin_amdgcn_fdot2(a, b, c, false);
#else
  return fmaf((float)a.x, (float)b.x, fmaf((float)a.y, (float)b.y, c));
#endif
}
__device__ __forceinline__ h2 bc_h2(unsigned int v) { return __builtin_bit_cast(h2, v); }
__device__ __forceinline__ unsigned int bc_u32(h2 v) { return __builtin_bit_cast(unsigned int, v); }
__device__ __forceinline__ ushort_t bc_u16(_Float16 v) { return __builtin_bit_cast(ushort_t, v); }

// ws layout (bytes):
//   wc16  [9][64][128] fp16 : off 0        size 147456   (conv1 weights, K-chunked)
//   pwB16 [64][160]    fp16 : off 147456   size 20480    (pconv weights, kk=k*48+ci)
//   Wh    [245760]     fp16 : off 167936   size 491520   (routing W)
//   u16   [4096][384][8] fp16: off 659456  size 25165824
// total ~25.8 MB

// ---------------- K0: weight prep ----------------
__global__ __launch_bounds__(256) void k0_prep(
    const float* __restrict__ w1, const float* __restrict__ pw,
    const float* __restrict__ Wf,
    _Float16* __restrict__ wc16, _Float16* __restrict__ pwB16,
    _Float16* __restrict__ Wh)
{
  int i = blockIdx.x * 256 + threadIdx.x;   // grid 960*256 = 245760
  if (i < 73728) {
    int c  = i / 8192;
    int r  = i % 8192;
    int co = r >> 7;
    int k  = r & 127;
    wc16[i] = (co < 50) ? (_Float16)w1[co*1152 + k*9 + c] : (_Float16)0.f;
  }
  if (i < 10240) {
    int co2 = i / 160, kk = i % 160;
    int k = kk / 48, ci = kk % 48;
    float v = (k < 3 && ci < 42) ? pw[co2*126 + ci*3 + k] : 0.f;
    pwB16[i] = (_Float16)v;
  }
  Wh[i] = (_Float16)Wf[i];
}

// ---------------- K12: MFMA conv1 + relu + MFMA pconv + squash (3 b per block) ----------------
__global__ __launch_bounds__(256) void k12_mfma(
    const float* __restrict__ x, const float* __restrict__ b1,
    const float* __restrict__ b2, const _Float16* __restrict__ wc16,
    const _Float16* __restrict__ pwB16, ushort_t* __restrict__ u16)
{
  __shared__ float smem[19728];
  _Float16* xh   = (_Float16*)smem;
  _Float16* hr16 = (_Float16*)smem;
  _Float16* pB   = (_Float16*)smem + 8736;
  float*    pbuf = smem + 9744;

  const int tid   = threadIdx.x;
  const int w     = tid >> 6;
  const int lane  = tid & 63;
  const int lc    = lane & 15;
  const int qd    = lane >> 4;
  const int gbase = blockIdx.x * 3;

  // ---- stage x: fp32 -> fp16 into padded rows ----
  for (int j = tid; j < 4800; j += 256) {
    int g = j / 1600, r = j - g*1600;
    int p = r >> 5, q = r & 31;
    int bb = gbase + g; if (bb > 4095) bb = 4095;
    float4 v = *(const float4*)(x + bb*6400 + p*128 + q*4);
    half4_t hv = {(_Float16)v.x, (_Float16)v.y, (_Float16)v.z, (_Float16)v.w};
    *(half4_t*)(xh + g*6800 + p*136 + q*4) = hv;
  }
  // ---- stage w chunk 0 into Bbuf0 ----
  {
    const uint4* wg = (const uint4*)wc16;
    uint4* dst = (uint4*)(xh + 20400);
#pragma unroll
    for (int it = 0; it < 4; ++it) {
      int f = it*256 + tid;
      dst[(f >> 4)*17 + (f & 15)] = wg[f];
    }
  }

  const _Float16* abase[2];
#pragma unroll
  for (int tm = 0; tm < 2; ++tm) {
    int m = 32*w + 16*tm + lc;
    if (m > 125) m = 125;
    int g = m / 42, l = m - g*42;
    abase[tm] = xh + g*6800 + l*136 + qd*8;
  }

  f32x4 acc[2][4];
#pragma unroll
  for (int tm = 0; tm < 2; ++tm)
#pragma unroll
    for (int tn = 0; tn < 4; ++tn)
      acc[tm][tn] = (f32x4){0.f, 0.f, 0.f, 0.f};

  __syncthreads();

  uint4 pf[4];
  for (int c = 0; c < 9; ++c) {
    if (c < 8) {
      const uint4* wg = (const uint4*)wc16 + (c + 1)*1024;
#pragma unroll
      for (int it = 0; it < 4; ++it) pf[it] = wg[it*256 + tid];
    }
    const _Float16* Bb = xh + 20400 + (c & 1)*8704;
    const _Float16* a0 = abase[0] + c*136;
    const _Float16* a1 = abase[1] + c*136;
#pragma unroll
    for (int kk = 0; kk < 128; kk += 32) {
      half8_t av0 = *(const half8_t*)(a0 + kk);
      half8_t av1 = *(const half8_t*)(a1 + kk);
#pragma unroll
      for (int tn = 0; tn < 4; ++tn) {
        half8_t bv = *(const half8_t*)(Bb + (16*tn + lc)*136 + qd*8 + kk);
        acc[0][tn] = __builtin_amdgcn_mfma_f32_16x16x32_f16(av0, bv, acc[0][tn], 0, 0, 0);
        acc[1][tn] = __builtin_amdgcn_mfma_f32_16x16x32_f16(av1, bv, acc[1][tn], 0, 0, 0);
      }
    }
    __syncthreads();
    if (c < 8) {
      uint4* dst = (uint4*)(xh + 20400 + ((c + 1) & 1)*8704);
#pragma unroll
      for (int it = 0; it < 4; ++it) {
        int f = it*256 + tid;
        dst[(f >> 4)*17 + (f & 15)] = pf[it];
      }
      __syncthreads();
    }
  }

  // ---- zero hr16 and stage pconv weights ----
  for (int j = tid; j < 4368; j += 256) smem[j] = 0.f;
  {
    const uint4* pg = (const uint4*)pwB16;
    uint4* dst = (uint4*)pB;
    for (int f = tid; f < 1280; f += 256) {
      int row = f / 20, cc = f - row*20;
      dst[row*21 + cc] = pg[f];
    }
  }
  __syncthreads();

  // ---- conv1 epilogue: bias+relu -> hr16[g][co][l] fp16 ----
#pragma unroll
  for (int tm = 0; tm < 2; ++tm) {
    int mb = 32*w + 16*tm + 4*qd;
#pragma unroll
    for (int tn = 0; tn < 4; ++tn) {
      int co = 16*tn + lc;
      if (co < 50) {
        float bias = b1[co];
#pragma unroll
        for (int r = 0; r < 4; ++r) {
          int m = mb + r;
          if (m < 126) {
            int g = m / 42, l = m - g*42;
            hr16[g*2912 + co*56 + l] = (_Float16)fmaxf(acc[tm][tn][r] + bias, 0.f);
          }
        }
      }
    }
  }
  __syncthreads();

  // ---- pconv MFMA: M=144, N=64, K=160 ----
  f32x4 acc2[3][4];
#pragma unroll
  for (int tm = 0; tm < 3; ++tm)
#pragma unroll
    for (int tn = 0; tn < 4; ++tn)
      acc2[tm][tn] = (f32x4){0.f, 0.f, 0.f, 0.f};

#pragma unroll
  for (int kc = 0; kc < 5; ++kc) {
    int kk0 = kc*32 + qd*8;
    int k   = (kk0 >= 144) ? 3 : (kk0 >= 96) ? 2 : (kk0 >= 48) ? 1 : 0;
    int ci0 = kk0 - k*48;
    half8_t bv[4];
#pragma unroll
    for (int tn = 0; tn < 4; ++tn)
      bv[tn] = *(const half8_t*)(pB + (16*tn + lc)*168 + kk0);
#pragma unroll
    for (int tm = 0; tm < 3; ++tm) {
      int T = w + 4*tm; int Tc = (T < 9) ? T : 8;
      int g = Tc/3, l2 = (Tc - g*3)*16 + lc;
      half8_t av = *(const half8_t*)(hr16 + g*2912 + (l2 + k)*56 + ci0);
#pragma unroll
      for (int tn = 0; tn < 4; ++tn)
        acc2[tm][tn] = __builtin_amdgcn_mfma_f32_16x16x32_f16(av, bv[tn], acc2[tm][tn], 0, 0, 0);
    }
  }

  // ---- pconv epilogue -> pbuf[g][co2][l2] ----
#pragma unroll
  for (int tm = 0; tm < 3; ++tm) {
    int T = w + 4*tm;
    if (T < 9) {
      int g = T/3, l2b = (T - g*3)*16;
#pragma unroll
      for (int tn = 0; tn < 4; ++tn) {
        int co2 = 16*tn + lc;
        float bias2 = b2[co2];
#pragma unroll
        for (int r = 0; r < 4; ++r) {
          int l2 = l2b + 4*qd + r;
          pbuf[g*3328 + co2*52 + l2] = acc2[tm][tn][r] + bias2;
        }
      }
    }
  }
  __syncthreads();

  // ---- squash all 3 g -> u16 (fp16) ----
  for (int idx = tid; idx < 1152; idx += 256) {
    int g = idx / 384, cap = idx - g*384;
    int bb = gbase + g;
    if (bb < 4096) {
      int co2 = cap / 6, gg = cap - co2*6;
      const float* pp = pbuf + g*3328 + co2*52 + gg*8;
      float4 a0 = *(const float4*)pp;
      float4 a1 = *(const float4*)(pp + 4);
      float sq = a0.x*a0.x + a0.y*a0.y + a0.z*a0.z + a0.w*a0.w
               + a1.x*a1.x + a1.y*a1.y + a1.z*a1.z + a1.w*a1.w;
      float sc = sq / ((1.f + sq) * (sqrtf(sq) + EPSQ));
      h2 p0 = {(_Float16)(a0.x*sc), (_Float16)(a0.y*sc)};
      h2 p1 = {(_Float16)(a0.z*sc), (_Float16)(a0.w*sc)};
      h2 p2 = {(_Float16)(a1.x*sc), (_Float16)(a1.y*sc)};
      h2 p3 = {(_Float16)(a1.z*sc), (_Float16)(a1.w*sc)};
      *(uint4*)(u16 + ((size_t)bb*384 + cap)*8) =
          make_uint4(bc_u32(p0), bc_u32(p1), bc_u32(p2), bc_u32(p3));
    }
  }
}

// ---------------- K3: u_hat + routing. NB=2 b per block, all-fp16 LDS, fdot2 ----------------
// LDS: uh16 2*80*416*2 = 133120 B, coc16 2*5*416*2 = 8320, svh 320, sv 640, ff 40 -> ~142.4 KB
__global__ __launch_bounds__(384) void k3_route(
    const ushort_t* __restrict__ u16, const _Float16* __restrict__ Wh,
    float* __restrict__ out)
{
  __shared__ __align__(16) ushort_t uh16[2][80][416];
  __shared__ __align__(16) ushort_t coc16[2][5][416];
  __shared__ __align__(16) ushort_t svh16[2][80];
  __shared__ float sv[2][80];
  __shared__ float ff[2][5];

  const int t  = threadIdx.x;
  const int b0 = blockIdx.x * 2;
  const int q  = t / 96;
  const int jc = t - q*96;
  const int ch = q*104 + jc;

  // load u (fp16) for both batches
  uint4 uu0 = *(const uint4*)(u16 + ((size_t)b0*384 + t)*8);
  uint4 uu1 = *(const uint4*)(u16 + ((size_t)(b0+1)*384 + t)*8);
  h2 ua0[4] = {bc_h2(uu0.x), bc_h2(uu0.y), bc_h2(uu0.z), bc_h2(uu0.w)};
  h2 ua1[4] = {bc_h2(uu1.x), bc_h2(uu1.y), bc_h2(uu1.z), bc_h2(uu1.w)};

  // ---- W-phase: u_hat for both b; uhreg packed half2 ----
  h2 uhreg[2][40];
#pragma unroll
  for (int o = 0; o < 5; ++o) {
    const uint4* wp = (const uint4*)(Wh + ((size_t)o*384 + t)*128);
#pragma unroll
    for (int dd = 0; dd < 8; ++dd) {
      uint4 w0 = wp[2*dd], w1 = wp[2*dd + 1];
      float s00 = fdot2f(bc_h2(w0.x), ua0[0], fdot2f(bc_h2(w0.y), ua0[1],
                  fdot2f(bc_h2(w0.z), ua0[2], fdot2f(bc_h2(w0.w), ua0[3], 0.f))));
      float s01 = fdot2f(bc_h2(w0.x), ua1[0], fdot2f(bc_h2(w0.y), ua1[1],
                  fdot2f(bc_h2(w0.z), ua1[2], fdot2f(bc_h2(w0.w), ua1[3], 0.f))));
      float s10 = fdot2f(bc_h2(w1.x), ua0[0], fdot2f(bc_h2(w1.y), ua0[1],
                  fdot2f(bc_h2(w1.z), ua0[2], fdot2f(bc_h2(w1.w), ua0[3], 0.f))));
      float s11 = fdot2f(bc_h2(w1.x), ua1[0], fdot2f(bc_h2(w1.y), ua1[1],
                  fdot2f(bc_h2(w1.z), ua1[2], fdot2f(bc_h2(w1.w), ua1[3], 0.f))));
      _Float16 f00 = (_Float16)s00, f10 = (_Float16)s10;
      _Float16 f01 = (_Float16)s01, f11 = (_Float16)s11;
      uh16[0][o*16 + 2*dd][ch]     = bc_u16(f00);
      uh16[0][o*16 + 2*dd + 1][ch] = bc_u16(f10);
      uh16[1][o*16 + 2*dd][ch]     = bc_u16(f01);
      uh16[1][o*16 + 2*dd + 1][ch] = bc_u16(f11);
      uhreg[0][o*8 + dd] = (h2){f00, f10};
      uhreg[1][o*8 + dd] = (h2){f01, f11};
    }
  }

  float lg[2][5] = {{0.f,0.f,0.f,0.f,0.f},{0.f,0.f,0.f,0.f,0.f}};
  uint4 ureg[2][12];   // s-phase uh strip cache (valid after it==0)

  for (int it = 0; it < 3; ++it) {
    // softmax over o per (b,c) -> coc16 fp16
#pragma unroll
    for (int bb = 0; bb < 2; ++bb) {
      float m = fmaxf(fmaxf(fmaxf(lg[bb][0],lg[bb][1]),fmaxf(lg[bb][2],lg[bb][3])),lg[bb][4]);
      float e[5]; float Z = 0.f;
#pragma unroll
      for (int o = 0; o < 5; ++o) { e[o] = __expf(lg[bb][o]-m); Z += e[o]; }
      float inv = 1.f / Z;
#pragma unroll
      for (int o = 0; o < 5; ++o) {
        _Float16 hc = (_Float16)(e[o]*inv);
        coc16[bb][o][ch] = bc_u16(hc);
      }
    }
    __syncthreads();

    // s-phase: thread (od,qq) dots a 96-c strip for both b; uh cached in regs
    if (t < 320) {
      int od = t >> 2, qq = t & 3, o = od >> 4;
#pragma unroll
      for (int bb = 0; bb < 2; ++bb) {
        if (it == 0) {
          const uint4* ua = (const uint4*)&uh16[bb][od][qq*104];
#pragma unroll
          for (int j = 0; j < 12; ++j) ureg[bb][j] = ua[j];
        }
        const uint4* ca = (const uint4*)&coc16[bb][o][qq*104];
        float sum = 0.f;
#pragma unroll
        for (int j = 0; j < 12; ++j) {
          uint4 uv = ureg[bb][j];
          uint4 cv = ca[j];
          sum = fdot2f(bc_h2(uv.x), bc_h2(cv.x), sum);
          sum = fdot2f(bc_h2(uv.y), bc_h2(cv.y), sum);
          sum = fdot2f(bc_h2(uv.z), bc_h2(cv.z), sum);
          sum = fdot2f(bc_h2(uv.w), bc_h2(cv.w), sum);
        }
        sum += __shfl_xor(sum, 1);
        sum += __shfl_xor(sum, 2);
        if (qq == 0) sv[bb][od] = sum;
      }
    }
    __syncthreads();

    // squash factor per (b,o); also emit svh16 = fp16(sv*f) for the uv-phase
    if (t < 10) {
      int bb = t / 5, o = t - bb*5;
      float sq = 0.f;
#pragma unroll
      for (int d = 0; d < 16; ++d) { float v = sv[bb][o*16+d]; sq = fmaf(v, v, sq); }
      float f = sq / ((1.f + sq) * (sqrtf(sq) + EPSQ));
      ff[bb][o] = f;
      if (it < 2) {
#pragma unroll
        for (int d = 0; d < 16; ++d) {
          _Float16 hf = (_Float16)(sv[bb][o*16+d] * f);
          svh16[bb][o*16+d] = bc_u16(hf);
        }
      }
    }
    __syncthreads();

    if (it == 2) {
      if (t < 160) {
        int bb = t / 80, od = t - bb*80;
        out[(size_t)(b0+bb)*80 + od] = sv[bb][od] * ff[bb][od >> 4];
      }
    } else {
      // logits update: dv = <tu, v> via packed fdot2 from registers + svh16
#pragma unroll
      for (int bb = 0; bb < 2; ++bb) {
#pragma unroll
        for (int o = 0; o < 5; ++o) {
          uint4 s0 = *(const uint4*)&svh16[bb][o*16];
          uint4 s1 = *(const uint4*)&svh16[bb][o*16 + 8];
          float dv = 0.f;
          dv = fdot2f(uhreg[bb][o*8+0], bc_h2(s0.x), dv);
          dv = fdot2f(uhreg[bb][o*8+1], bc_h2(s0.y), dv);
          dv = fdot2f(uhreg[bb][o*8+2], bc_h2(s0.z), dv);
          dv = fdot2f(uhreg[bb][o*8+3], bc_h2(s0.w), dv);
          dv = fdot2f(uhreg[bb][o*8+4], bc_h2(s1.x), dv);
          dv = fdot2f(uhreg[bb][o*8+5], bc_h2(s1.y), dv);
          dv = fdot2f(uhreg[bb][o*8+6], bc_h2(s1.z), dv);
          dv = fdot2f(uhreg[bb][o*8+7], bc_h2(s1.w), dv);
          lg[bb][o] += dv;
        }
      }
    }
  }
}

extern "C" void kernel_launch(void* const* d_in, const int* in_sizes, int n_in,
                              void* d_out, int out_size, void* d_ws, size_t ws_size,
                              hipStream_t stream) {
  const float* x  = (const float*)d_in[0];
  const float* w1 = (const float*)d_in[1];
  const float* b1 = (const float*)d_in[2];
  const float* pw = (const float*)d_in[3];
  const float* b2 = (const float*)d_in[4];
  const float* Wf = (const float*)d_in[5];
  float* out = (float*)d_out;
  char* ws = (char*)d_ws;

  _Float16* wc16  = (_Float16*)(ws);
  _Float16* pwB16 = (_Float16*)(ws + 147456);
  _Float16* Wh    = (_Float16*)(ws + 167936);
  ushort_t* u16   = (ushort_t*)(ws + 659456);

  k0_prep<<<960, 256, 0, stream>>>(w1, pw, Wf, wc16, pwB16, Wh);
  k12_mfma<<<1366, 256, 0, stream>>>(x, b1, b2, wc16, pwB16, u16);
  k3_route<<<2048, 384, 0, stream>>>(u16, Wh, out);
}

// Round 7
// 449.228 us; speedup vs baseline: 8.1704x; 1.0008x over previous
//
#include <hip/hip_runtime.h>
#include <hip/hip_bf16.h>

typedef unsigned short ushort_t;
typedef _Float16 h2 __attribute__((ext_vector_type(2)));
typedef _Float16 half4_t __attribute__((ext_vector_type(4)));
typedef _Float16 half8_t __attribute__((ext_vector_type(8)));
typedef float f32x4 __attribute__((ext_vector_type(4)));
#define EPSQ 1e-8f

__device__ __forceinline__ float fdot2f(h2 a, h2 b, float c) {
#if __has_builtin(__builtin_amdgcn_fdot2)
  return __builtin_amdgcn_fdot2(a, b, c, false);
#else
  return fmaf((float)a.x, (float)b.x, fmaf((float)a.y, (float)b.y, c));
#endif
}
__device__ __forceinline__ h2 bc_h2(unsigned int v) { return __builtin_bit_cast(h2, v); }
__device__ __forceinline__ unsigned int bc_u32(h2 v) { return __builtin_bit_cast(unsigned int, v); }
__device__ __forceinline__ ushort_t bc_u16(_Float16 v) { return __builtin_bit_cast(ushort_t, v); }

// ws layout (bytes):
//   wc16  [9][64][128] fp16 : off 0        size 147456   (conv1 weights, K-chunked)
//   pwB16 [64][160]    fp16 : off 147456   size 20480    (pconv weights, kk=k*48+ci)
//   Wh    [245760]     fp16 : off 167936   size 491520   (routing W)
//   u16   [4096][384][8] fp16: off 659456  size 25165824
// total ~25.8 MB

// ---------------- K0: weight prep ----------------
__global__ __launch_bounds__(256) void k0_prep(
    const float* __restrict__ w1, const float* __restrict__ pw,
    const float* __restrict__ Wf,
    _Float16* __restrict__ wc16, _Float16* __restrict__ pwB16,
    _Float16* __restrict__ Wh)
{
  int i = blockIdx.x * 256 + threadIdx.x;   // grid 960*256 = 245760
  if (i < 73728) {
    int c  = i / 8192;
    int r  = i % 8192;
    int co = r >> 7;
    int k  = r & 127;
    wc16[i] = (co < 50) ? (_Float16)w1[co*1152 + k*9 + c] : (_Float16)0.f;
  }
  if (i < 10240) {
    int co2 = i / 160, kk = i % 160;
    int k = kk / 48, ci = kk % 48;
    float v = (k < 3 && ci < 42) ? pw[co2*126 + ci*3 + k] : 0.f;
    pwB16[i] = (_Float16)v;
  }
  Wh[i] = (_Float16)Wf[i];
}

// ---------------- K12: MFMA conv1 + relu + MFMA pconv + squash (3 b per block) ----------------
__global__ __launch_bounds__(256) void k12_mfma(
    const float* __restrict__ x, const float* __restrict__ b1,
    const float* __restrict__ b2, const _Float16* __restrict__ wc16,
    const _Float16* __restrict__ pwB16, ushort_t* __restrict__ u16)
{
  __shared__ float smem[19728];
  _Float16* xh   = (_Float16*)smem;
  _Float16* hr16 = (_Float16*)smem;
  _Float16* pB   = (_Float16*)smem + 8736;
  float*    pbuf = smem + 9744;

  const int tid   = threadIdx.x;
  const int w     = tid >> 6;
  const int lane  = tid & 63;
  const int lc    = lane & 15;
  const int qd    = lane >> 4;
  const int gbase = blockIdx.x * 3;

  // ---- stage x: fp32 -> fp16 into padded rows ----
  for (int j = tid; j < 4800; j += 256) {
    int g = j / 1600, r = j - g*1600;
    int p = r >> 5, q = r & 31;
    int bb = gbase + g; if (bb > 4095) bb = 4095;
    float4 v = *(const float4*)(x + bb*6400 + p*128 + q*4);
    half4_t hv = {(_Float16)v.x, (_Float16)v.y, (_Float16)v.z, (_Float16)v.w};
    *(half4_t*)(xh + g*6800 + p*136 + q*4) = hv;
  }
  // ---- stage w chunk 0 into Bbuf0 ----
  {
    const uint4* wg = (const uint4*)wc16;
    uint4* dst = (uint4*)(xh + 20400);
#pragma unroll
    for (int it = 0; it < 4; ++it) {
      int f = it*256 + tid;
      dst[(f >> 4)*17 + (f & 15)] = wg[f];
    }
  }

  const _Float16* abase[2];
#pragma unroll
  for (int tm = 0; tm < 2; ++tm) {
    int m = 32*w + 16*tm + lc;
    if (m > 125) m = 125;
    int g = m / 42, l = m - g*42;
    abase[tm] = xh + g*6800 + l*136 + qd*8;
  }

  f32x4 acc[2][4];
#pragma unroll
  for (int tm = 0; tm < 2; ++tm)
#pragma unroll
    for (int tn = 0; tn < 4; ++tn)
      acc[tm][tn] = (f32x4){0.f, 0.f, 0.f, 0.f};

  __syncthreads();

  uint4 pf[4];
  for (int c = 0; c < 9; ++c) {
    if (c < 8) {
      const uint4* wg = (const uint4*)wc16 + (c + 1)*1024;
#pragma unroll
      for (int it = 0; it < 4; ++it) pf[it] = wg[it*256 + tid];
    }
    const _Float16* Bb = xh + 20400 + (c & 1)*8704;
    const _Float16* a0 = abase[0] + c*136;
    const _Float16* a1 = abase[1] + c*136;
#pragma unroll
    for (int kk = 0; kk < 128; kk += 32) {
      half8_t av0 = *(const half8_t*)(a0 + kk);
      half8_t av1 = *(const half8_t*)(a1 + kk);
#pragma unroll
      for (int tn = 0; tn < 4; ++tn) {
        half8_t bv = *(const half8_t*)(Bb + (16*tn + lc)*136 + qd*8 + kk);
        acc[0][tn] = __builtin_amdgcn_mfma_f32_16x16x32_f16(av0, bv, acc[0][tn], 0, 0, 0);
        acc[1][tn] = __builtin_amdgcn_mfma_f32_16x16x32_f16(av1, bv, acc[1][tn], 0, 0, 0);
      }
    }
    __syncthreads();
    if (c < 8) {
      uint4* dst = (uint4*)(xh + 20400 + ((c + 1) & 1)*8704);
#pragma unroll
      for (int it = 0; it < 4; ++it) {
        int f = it*256 + tid;
        dst[(f >> 4)*17 + (f & 15)] = pf[it];
      }
      __syncthreads();
    }
  }

  // ---- zero hr16 and stage pconv weights ----
  for (int j = tid; j < 4368; j += 256) smem[j] = 0.f;
  {
    const uint4* pg = (const uint4*)pwB16;
    uint4* dst = (uint4*)pB;
    for (int f = tid; f < 1280; f += 256) {
      int row = f / 20, cc = f - row*20;
      dst[row*21 + cc] = pg[f];
    }
  }
  __syncthreads();

  // ---- conv1 epilogue: bias+relu -> hr16[g][co][l] fp16 ----
#pragma unroll
  for (int tm = 0; tm < 2; ++tm) {
    int mb = 32*w + 16*tm + 4*qd;
#pragma unroll
    for (int tn = 0; tn < 4; ++tn) {
      int co = 16*tn + lc;
      if (co < 50) {
        float bias = b1[co];
#pragma unroll
        for (int r = 0; r < 4; ++r) {
          int m = mb + r;
          if (m < 126) {
            int g = m / 42, l = m - g*42;
            hr16[g*2912 + co*56 + l] = (_Float16)fmaxf(acc[tm][tn][r] + bias, 0.f);
          }
        }
      }
    }
  }
  __syncthreads();

  // ---- pconv MFMA: M=144, N=64, K=160 ----
  f32x4 acc2[3][4];
#pragma unroll
  for (int tm = 0; tm < 3; ++tm)
#pragma unroll
    for (int tn = 0; tn < 4; ++tn)
      acc2[tm][tn] = (f32x4){0.f, 0.f, 0.f, 0.f};

#pragma unroll
  for (int kc = 0; kc < 5; ++kc) {
    int kk0 = kc*32 + qd*8;
    int k   = (kk0 >= 144) ? 3 : (kk0 >= 96) ? 2 : (kk0 >= 48) ? 1 : 0;
    int ci0 = kk0 - k*48;
    half8_t bv[4];
#pragma unroll
    for (int tn = 0; tn < 4; ++tn)
      bv[tn] = *(const half8_t*)(pB + (16*tn + lc)*168 + kk0);
#pragma unroll
    for (int tm = 0; tm < 3; ++tm) {
      int T = w + 4*tm; int Tc = (T < 9) ? T : 8;
      int g = Tc/3, l2 = (Tc - g*3)*16 + lc;
      half8_t av = *(const half8_t*)(hr16 + g*2912 + (l2 + k)*56 + ci0);
#pragma unroll
      for (int tn = 0; tn < 4; ++tn)
        acc2[tm][tn] = __builtin_amdgcn_mfma_f32_16x16x32_f16(av, bv[tn], acc2[tm][tn], 0, 0, 0);
    }
  }

  // ---- pconv epilogue -> pbuf[g][co2][l2] ----
#pragma unroll
  for (int tm = 0; tm < 3; ++tm) {
    int T = w + 4*tm;
    if (T < 9) {
      int g = T/3, l2b = (T - g*3)*16;
#pragma unroll
      for (int tn = 0; tn < 4; ++tn) {
        int co2 = 16*tn + lc;
        float bias2 = b2[co2];
#pragma unroll
        for (int r = 0; r < 4; ++r) {
          int l2 = l2b + 4*qd + r;
          pbuf[g*3328 + co2*52 + l2] = acc2[tm][tn][r] + bias2;
        }
      }
    }
  }
  __syncthreads();

  // ---- squash all 3 g -> u16 (fp16) ----
  for (int idx = tid; idx < 1152; idx += 256) {
    int g = idx / 384, cap = idx - g*384;
    int bb = gbase + g;
    if (bb < 4096) {
      int co2 = cap / 6, gg = cap - co2*6;
      const float* pp = pbuf + g*3328 + co2*52 + gg*8;
      float4 a0 = *(const float4*)pp;
      float4 a1 = *(const float4*)(pp + 4);
      float sq = a0.x*a0.x + a0.y*a0.y + a0.z*a0.z + a0.w*a0.w
               + a1.x*a1.x + a1.y*a1.y + a1.z*a1.z + a1.w*a1.w;
      float sc = sq / ((1.f + sq) * (sqrtf(sq) + EPSQ));
      h2 p0 = {(_Float16)(a0.x*sc), (_Float16)(a0.y*sc)};
      h2 p1 = {(_Float16)(a0.z*sc), (_Float16)(a0.w*sc)};
      h2 p2 = {(_Float16)(a1.x*sc), (_Float16)(a1.y*sc)};
      h2 p3 = {(_Float16)(a1.z*sc), (_Float16)(a1.w*sc)};
      *(uint4*)(u16 + ((size_t)bb*384 + cap)*8) =
          make_uint4(bc_u32(p0), bc_u32(p1), bc_u32(p2), bc_u32(p3));
    }
  }
}

// ---------------- K3: u_hat + routing. NB=2 b per block, all-fp16 LDS, fdot2 ----------------
// __launch_bounds__(384, 2): 2 waves/EU -> VGPR cap 256 (R6's cap of 128 spilled
// ureg+uhreg (~210 VGPRs demand) to HBM scratch: 67 MB WRITE_SIZE, the whole kernel).
__global__ __launch_bounds__(384, 2) void k3_route(
    const ushort_t* __restrict__ u16, const _Float16* __restrict__ Wh,
    float* __restrict__ out)
{
  __shared__ __align__(16) ushort_t uh16[2][80][416];
  __shared__ __align__(16) ushort_t coc16[2][5][416];
  __shared__ __align__(16) ushort_t svh16[2][80];
  __shared__ float sv[2][80];
  __shared__ float ff[2][5];

  const int t  = threadIdx.x;
  const int b0 = blockIdx.x * 2;
  const int q  = t / 96;
  const int jc = t - q*96;
  const int ch = q*104 + jc;

  // load u (fp16) for both batches
  uint4 uu0 = *(const uint4*)(u16 + ((size_t)b0*384 + t)*8);
  uint4 uu1 = *(const uint4*)(u16 + ((size_t)(b0+1)*384 + t)*8);
  h2 ua0[4] = {bc_h2(uu0.x), bc_h2(uu0.y), bc_h2(uu0.z), bc_h2(uu0.w)};
  h2 ua1[4] = {bc_h2(uu1.x), bc_h2(uu1.y), bc_h2(uu1.z), bc_h2(uu1.w)};

  // ---- W-phase: u_hat for both b; uhreg packed half2 ----
  h2 uhreg[2][40];
#pragma unroll
  for (int o = 0; o < 5; ++o) {
    const uint4* wp = (const uint4*)(Wh + ((size_t)o*384 + t)*128);
#pragma unroll
    for (int dd = 0; dd < 8; ++dd) {
      uint4 w0 = wp[2*dd], w1 = wp[2*dd + 1];
      float s00 = fdot2f(bc_h2(w0.x), ua0[0], fdot2f(bc_h2(w0.y), ua0[1],
                  fdot2f(bc_h2(w0.z), ua0[2], fdot2f(bc_h2(w0.w), ua0[3], 0.f))));
      float s01 = fdot2f(bc_h2(w0.x), ua1[0], fdot2f(bc_h2(w0.y), ua1[1],
                  fdot2f(bc_h2(w0.z), ua1[2], fdot2f(bc_h2(w0.w), ua1[3], 0.f))));
      float s10 = fdot2f(bc_h2(w1.x), ua0[0], fdot2f(bc_h2(w1.y), ua0[1],
                  fdot2f(bc_h2(w1.z), ua0[2], fdot2f(bc_h2(w1.w), ua0[3], 0.f))));
      float s11 = fdot2f(bc_h2(w1.x), ua1[0], fdot2f(bc_h2(w1.y), ua1[1],
                  fdot2f(bc_h2(w1.z), ua1[2], fdot2f(bc_h2(w1.w), ua1[3], 0.f))));
      _Float16 f00 = (_Float16)s00, f10 = (_Float16)s10;
      _Float16 f01 = (_Float16)s01, f11 = (_Float16)s11;
      uh16[0][o*16 + 2*dd][ch]     = bc_u16(f00);
      uh16[0][o*16 + 2*dd + 1][ch] = bc_u16(f10);
      uh16[1][o*16 + 2*dd][ch]     = bc_u16(f01);
      uh16[1][o*16 + 2*dd + 1][ch] = bc_u16(f11);
      uhreg[0][o*8 + dd] = (h2){f00, f10};
      uhreg[1][o*8 + dd] = (h2){f01, f11};
    }
  }

  float lg[2][5] = {{0.f,0.f,0.f,0.f,0.f},{0.f,0.f,0.f,0.f,0.f}};
  uint4 ureg[2][12];   // s-phase uh strip cache (valid after it==0)

  for (int it = 0; it < 3; ++it) {
    // softmax over o per (b,c) -> coc16 fp16
#pragma unroll
    for (int bb = 0; bb < 2; ++bb) {
      float m = fmaxf(fmaxf(fmaxf(lg[bb][0],lg[bb][1]),fmaxf(lg[bb][2],lg[bb][3])),lg[bb][4]);
      float e[5]; float Z = 0.f;
#pragma unroll
      for (int o = 0; o < 5; ++o) { e[o] = __expf(lg[bb][o]-m); Z += e[o]; }
      float inv = 1.f / Z;
#pragma unroll
      for (int o = 0; o < 5; ++o) {
        _Float16 hc = (_Float16)(e[o]*inv);
        coc16[bb][o][ch] = bc_u16(hc);
      }
    }
    __syncthreads();

    // s-phase: thread (od,qq) dots a 96-c strip for both b; uh cached in regs
    if (t < 320) {
      int od = t >> 2, qq = t & 3, o = od >> 4;
#pragma unroll
      for (int bb = 0; bb < 2; ++bb) {
        if (it == 0) {
          const uint4* ua = (const uint4*)&uh16[bb][od][qq*104];
#pragma unroll
          for (int j = 0; j < 12; ++j) ureg[bb][j] = ua[j];
        }
        const uint4* ca = (const uint4*)&coc16[bb][o][qq*104];
        float sum = 0.f;
#pragma unroll
        for (int j = 0; j < 12; ++j) {
          uint4 uv = ureg[bb][j];
          uint4 cv = ca[j];
          sum = fdot2f(bc_h2(uv.x), bc_h2(cv.x), sum);
          sum = fdot2f(bc_h2(uv.y), bc_h2(cv.y), sum);
          sum = fdot2f(bc_h2(uv.z), bc_h2(cv.z), sum);
          sum = fdot2f(bc_h2(uv.w), bc_h2(cv.w), sum);
        }
        sum += __shfl_xor(sum, 1);
        sum += __shfl_xor(sum, 2);
        if (qq == 0) sv[bb][od] = sum;
      }
    }
    __syncthreads();

    // squash factor per (b,o); also emit svh16 = fp16(sv*f) for the uv-phase
    if (t < 10) {
      int bb = t / 5, o = t - bb*5;
      float sq = 0.f;
#pragma unroll
      for (int d = 0; d < 16; ++d) { float v = sv[bb][o*16+d]; sq = fmaf(v, v, sq); }
      float f = sq / ((1.f + sq) * (sqrtf(sq) + EPSQ));
      ff[bb][o] = f;
      if (it < 2) {
#pragma unroll
        for (int d = 0; d < 16; ++d) {
          _Float16 hf = (_Float16)(sv[bb][o*16+d] * f);
          svh16[bb][o*16+d] = bc_u16(hf);
        }
      }
    }
    __syncthreads();

    if (it == 2) {
      if (t < 160) {
        int bb = t / 80, od = t - bb*80;
        out[(size_t)(b0+bb)*80 + od] = sv[bb][od] * ff[bb][od >> 4];
      }
    } else {
      // logits update: dv = <tu, v> via packed fdot2 from registers + svh16
#pragma unroll
      for (int bb = 0; bb < 2; ++bb) {
#pragma unroll
        for (int o = 0; o < 5; ++o) {
          uint4 s0 = *(const uint4*)&svh16[bb][o*16];
          uint4 s1 = *(const uint4*)&svh16[bb][o*16 + 8];
          float dv = 0.f;
          dv = fdot2f(uhreg[bb][o*8+0], bc_h2(s0.x), dv);
          dv = fdot2f(uhreg[bb][o*8+1], bc_h2(s0.y), dv);
          dv = fdot2f(uhreg[bb][o*8+2], bc_h2(s0.z), dv);
          dv = fdot2f(uhreg[bb][o*8+3], bc_h2(s0.w), dv);
          dv = fdot2f(uhreg[bb][o*8+4], bc_h2(s1.x), dv);
          dv = fdot2f(uhreg[bb][o*8+5], bc_h2(s1.y), dv);
          dv = fdot2f(uhreg[bb][o*8+6], bc_h2(s1.z), dv);
          dv = fdot2f(uhreg[bb][o*8+7], bc_h2(s1.w), dv);
          lg[bb][o] += dv;
        }
      }
    }
  }
}

extern "C" void kernel_launch(void* const* d_in, const int* in_sizes, int n_in,
                              void* d_out, int out_size, void* d_ws, size_t ws_size,
                              hipStream_t stream) {
  const float* x  = (const float*)d_in[0];
  const float* w1 = (const float*)d_in[1];
  const float* b1 = (const float*)d_in[2];
  const float* pw = (const float*)d_in[3];
  const float* b2 = (const float*)d_in[4];
  const float* Wf = (const float*)d_in[5];
  float* out = (float*)d_out;
  char* ws = (char*)d_ws;

  _Float16* wc16  = (_Float16*)(ws);
  _Float16* pwB16 = (_Float16*)(ws + 147456);
  _Float16* Wh    = (_Float16*)(ws + 167936);
  ushort_t* u16   = (ushort_t*)(ws + 659456);

  k0_prep<<<960, 256, 0, stream>>>(w1, pw, Wf, wc16, pwB16, Wh);
  k12_mfma<<<1366, 256, 0, stream>>>(x, b1, b2, wc16, pwB16, u16);
  k3_route<<<2048, 384, 0, stream>>>(u16, Wh, out);
}

// Round 8
// 424.441 us; speedup vs baseline: 8.6476x; 1.0584x over previous
//
#include <hip/hip_runtime.h>
#include <hip/hip_bf16.h>

typedef unsigned short ushort_t;
typedef _Float16 h2 __attribute__((ext_vector_type(2)));
typedef _Float16 half4_t __attribute__((ext_vector_type(4)));
typedef _Float16 half8_t __attribute__((ext_vector_type(8)));
typedef float f32x4 __attribute__((ext_vector_type(4)));
#define EPSQ 1e-8f

__device__ __forceinline__ float fdot2f(h2 a, h2 b, float c) {
#if __has_builtin(__builtin_amdgcn_fdot2)
  return __builtin_amdgcn_fdot2(a, b, c, false);
#else
  return fmaf((float)a.x, (float)b.x, fmaf((float)a.y, (float)b.y, c));
#endif
}
__device__ __forceinline__ h2 bc_h2(unsigned int v) { return __builtin_bit_cast(h2, v); }
__device__ __forceinline__ unsigned int bc_u32(h2 v) { return __builtin_bit_cast(unsigned int, v); }
__device__ __forceinline__ ushort_t bc_u16(_Float16 v) { return __builtin_bit_cast(ushort_t, v); }

// ws layout (bytes):
//   wc16  [9][64][128] fp16 : off 0        size 147456   (conv1 weights, K-chunked)
//   pwB16 [64][160]    fp16 : off 147456   size 20480    (pconv weights, kk=k*48+ci)
//   Wh    [245760]     fp16 : off 167936   size 491520   (routing W)
//   u16   [4096][384][8] fp16: off 659456  size 25165824
// total ~25.8 MB

// ---------------- K0: weight prep ----------------
__global__ __launch_bounds__(256) void k0_prep(
    const float* __restrict__ w1, const float* __restrict__ pw,
    const float* __restrict__ Wf,
    _Float16* __restrict__ wc16, _Float16* __restrict__ pwB16,
    _Float16* __restrict__ Wh)
{
  int i = blockIdx.x * 256 + threadIdx.x;   // grid 960*256 = 245760
  if (i < 73728) {
    int c  = i / 8192;
    int r  = i % 8192;
    int co = r >> 7;
    int k  = r & 127;
    wc16[i] = (co < 50) ? (_Float16)w1[co*1152 + k*9 + c] : (_Float16)0.f;
  }
  if (i < 10240) {
    int co2 = i / 160, kk = i % 160;
    int k = kk / 48, ci = kk % 48;
    float v = (k < 3 && ci < 42) ? pw[co2*126 + ci*3 + k] : 0.f;
    pwB16[i] = (_Float16)v;
  }
  Wh[i] = (_Float16)Wf[i];
}

// ---------------- K12: MFMA conv1 + relu + MFMA pconv + squash (3 b per block) ----------------
__global__ __launch_bounds__(256) void k12_mfma(
    const float* __restrict__ x, const float* __restrict__ b1,
    const float* __restrict__ b2, const _Float16* __restrict__ wc16,
    const _Float16* __restrict__ pwB16, ushort_t* __restrict__ u16)
{
  __shared__ float smem[19728];
  _Float16* xh   = (_Float16*)smem;
  _Float16* hr16 = (_Float16*)smem;
  _Float16* pB   = (_Float16*)smem + 8736;
  float*    pbuf = smem + 9744;

  const int tid   = threadIdx.x;
  const int w     = tid >> 6;
  const int lane  = tid & 63;
  const int lc    = lane & 15;
  const int qd    = lane >> 4;
  const int gbase = blockIdx.x * 3;

  // ---- stage x: fp32 -> fp16 into padded rows ----
  for (int j = tid; j < 4800; j += 256) {
    int g = j / 1600, r = j - g*1600;
    int p = r >> 5, q = r & 31;
    int bb = gbase + g; if (bb > 4095) bb = 4095;
    float4 v = *(const float4*)(x + bb*6400 + p*128 + q*4);
    half4_t hv = {(_Float16)v.x, (_Float16)v.y, (_Float16)v.z, (_Float16)v.w};
    *(half4_t*)(xh + g*6800 + p*136 + q*4) = hv;
  }
  // ---- stage w chunk 0 into Bbuf0 ----
  {
    const uint4* wg = (const uint4*)wc16;
    uint4* dst = (uint4*)(xh + 20400);
#pragma unroll
    for (int it = 0; it < 4; ++it) {
      int f = it*256 + tid;
      dst[(f >> 4)*17 + (f & 15)] = wg[f];
    }
  }

  const _Float16* abase[2];
#pragma unroll
  for (int tm = 0; tm < 2; ++tm) {
    int m = 32*w + 16*tm + lc;
    if (m > 125) m = 125;
    int g = m / 42, l = m - g*42;
    abase[tm] = xh + g*6800 + l*136 + qd*8;
  }

  f32x4 acc[2][4];
#pragma unroll
  for (int tm = 0; tm < 2; ++tm)
#pragma unroll
    for (int tn = 0; tn < 4; ++tn)
      acc[tm][tn] = (f32x4){0.f, 0.f, 0.f, 0.f};

  __syncthreads();

  uint4 pf[4];
  for (int c = 0; c < 9; ++c) {
    if (c < 8) {
      const uint4* wg = (const uint4*)wc16 + (c + 1)*1024;
#pragma unroll
      for (int it = 0; it < 4; ++it) pf[it] = wg[it*256 + tid];
    }
    const _Float16* Bb = xh + 20400 + (c & 1)*8704;
    const _Float16* a0 = abase[0] + c*136;
    const _Float16* a1 = abase[1] + c*136;
#pragma unroll
    for (int kk = 0; kk < 128; kk += 32) {
      half8_t av0 = *(const half8_t*)(a0 + kk);
      half8_t av1 = *(const half8_t*)(a1 + kk);
#pragma unroll
      for (int tn = 0; tn < 4; ++tn) {
        half8_t bv = *(const half8_t*)(Bb + (16*tn + lc)*136 + qd*8 + kk);
        acc[0][tn] = __builtin_amdgcn_mfma_f32_16x16x32_f16(av0, bv, acc[0][tn], 0, 0, 0);
        acc[1][tn] = __builtin_amdgcn_mfma_f32_16x16x32_f16(av1, bv, acc[1][tn], 0, 0, 0);
      }
    }
    __syncthreads();
    if (c < 8) {
      uint4* dst = (uint4*)(xh + 20400 + ((c + 1) & 1)*8704);
#pragma unroll
      for (int it = 0; it < 4; ++it) {
        int f = it*256 + tid;
        dst[(f >> 4)*17 + (f & 15)] = pf[it];
      }
      __syncthreads();
    }
  }

  // ---- zero hr16 and stage pconv weights ----
  for (int j = tid; j < 4368; j += 256) smem[j] = 0.f;
  {
    const uint4* pg = (const uint4*)pwB16;
    uint4* dst = (uint4*)pB;
    for (int f = tid; f < 1280; f += 256) {
      int row = f / 20, cc = f - row*20;
      dst[row*21 + cc] = pg[f];
    }
  }
  __syncthreads();

  // ---- conv1 epilogue: bias+relu -> hr16[g][co][l] fp16 ----
#pragma unroll
  for (int tm = 0; tm < 2; ++tm) {
    int mb = 32*w + 16*tm + 4*qd;
#pragma unroll
    for (int tn = 0; tn < 4; ++tn) {
      int co = 16*tn + lc;
      if (co < 50) {
        float bias = b1[co];
#pragma unroll
        for (int r = 0; r < 4; ++r) {
          int m = mb + r;
          if (m < 126) {
            int g = m / 42, l = m - g*42;
            hr16[g*2912 + co*56 + l] = (_Float16)fmaxf(acc[tm][tn][r] + bias, 0.f);
          }
        }
      }
    }
  }
  __syncthreads();

  // ---- pconv MFMA: M=144, N=64, K=160 ----
  f32x4 acc2[3][4];
#pragma unroll
  for (int tm = 0; tm < 3; ++tm)
#pragma unroll
    for (int tn = 0; tn < 4; ++tn)
      acc2[tm][tn] = (f32x4){0.f, 0.f, 0.f, 0.f};

#pragma unroll
  for (int kc = 0; kc < 5; ++kc) {
    int kk0 = kc*32 + qd*8;
    int k   = (kk0 >= 144) ? 3 : (kk0 >= 96) ? 2 : (kk0 >= 48) ? 1 : 0;
    int ci0 = kk0 - k*48;
    half8_t bv[4];
#pragma unroll
    for (int tn = 0; tn < 4; ++tn)
      bv[tn] = *(const half8_t*)(pB + (16*tn + lc)*168 + kk0);
#pragma unroll
    for (int tm = 0; tm < 3; ++tm) {
      int T = w + 4*tm; int Tc = (T < 9) ? T : 8;
      int g = Tc/3, l2 = (Tc - g*3)*16 + lc;
      half8_t av = *(const half8_t*)(hr16 + g*2912 + (l2 + k)*56 + ci0);
#pragma unroll
      for (int tn = 0; tn < 4; ++tn)
        acc2[tm][tn] = __builtin_amdgcn_mfma_f32_16x16x32_f16(av, bv[tn], acc2[tm][tn], 0, 0, 0);
    }
  }

  // ---- pconv epilogue -> pbuf[g][co2][l2] ----
#pragma unroll
  for (int tm = 0; tm < 3; ++tm) {
    int T = w + 4*tm;
    if (T < 9) {
      int g = T/3, l2b = (T - g*3)*16;
#pragma unroll
      for (int tn = 0; tn < 4; ++tn) {
        int co2 = 16*tn + lc;
        float bias2 = b2[co2];
#pragma unroll
        for (int r = 0; r < 4; ++r) {
          int l2 = l2b + 4*qd + r;
          pbuf[g*3328 + co2*52 + l2] = acc2[tm][tn][r] + bias2;
        }
      }
    }
  }
  __syncthreads();

  // ---- squash all 3 g -> u16 (fp16) ----
  for (int idx = tid; idx < 1152; idx += 256) {
    int g = idx / 384, cap = idx - g*384;
    int bb = gbase + g;
    if (bb < 4096) {
      int co2 = cap / 6, gg = cap - co2*6;
      const float* pp = pbuf + g*3328 + co2*52 + gg*8;
      float4 a0 = *(const float4*)pp;
      float4 a1 = *(const float4*)(pp + 4);
      float sq = a0.x*a0.x + a0.y*a0.y + a0.z*a0.z + a0.w*a0.w
               + a1.x*a1.x + a1.y*a1.y + a1.z*a1.z + a1.w*a1.w;
      float sc = sq / ((1.f + sq) * (sqrtf(sq) + EPSQ));
      h2 p0 = {(_Float16)(a0.x*sc), (_Float16)(a0.y*sc)};
      h2 p1 = {(_Float16)(a0.z*sc), (_Float16)(a0.w*sc)};
      h2 p2 = {(_Float16)(a1.x*sc), (_Float16)(a1.y*sc)};
      h2 p3 = {(_Float16)(a1.z*sc), (_Float16)(a1.w*sc)};
      *(uint4*)(u16 + ((size_t)bb*384 + cap)*8) =
          make_uint4(bc_u32(p0), bc_u32(p1), bc_u32(p2), bc_u32(p3));
    }
  }
}

// ---------------- K3: u_hat + routing. NB=2 b per block, all-fp16 LDS, fdot2 ----------------
// R7 post-mortem: ureg[2][12] uint4 (96 VGPRs) + uhreg (80) blew the 128-VGPR cap ->
// 67 MB scratch spill = the whole kernel's runtime. ureg dropped; s-phase reads uh16
// from LDS each iteration (2-way bank aliasing only = free). uhreg kept (uv-phase
// needs register-resident tu; LDS alternative is 320 scalar b16 column reads).
__global__ __launch_bounds__(384) void k3_route(
    const ushort_t* __restrict__ u16, const _Float16* __restrict__ Wh,
    float* __restrict__ out)
{
  __shared__ __align__(16) ushort_t uh16[2][80][416];
  __shared__ __align__(16) ushort_t coc16[2][5][416];
  __shared__ __align__(16) ushort_t svh16[2][80];
  __shared__ float sv[2][80];
  __shared__ float ff[2][5];

  const int t  = threadIdx.x;
  const int b0 = blockIdx.x * 2;
  const int q  = t / 96;
  const int jc = t - q*96;
  const int ch = q*104 + jc;

  // load u (fp16) for both batches
  uint4 uu0 = *(const uint4*)(u16 + ((size_t)b0*384 + t)*8);
  uint4 uu1 = *(const uint4*)(u16 + ((size_t)(b0+1)*384 + t)*8);
  h2 ua0[4] = {bc_h2(uu0.x), bc_h2(uu0.y), bc_h2(uu0.z), bc_h2(uu0.w)};
  h2 ua1[4] = {bc_h2(uu1.x), bc_h2(uu1.y), bc_h2(uu1.z), bc_h2(uu1.w)};

  // ---- W-phase: u_hat for both b; uhreg packed half2 ----
  h2 uhreg[2][40];
#pragma unroll
  for (int o = 0; o < 5; ++o) {
    const uint4* wp = (const uint4*)(Wh + ((size_t)o*384 + t)*128);
#pragma unroll
    for (int dd = 0; dd < 8; ++dd) {
      uint4 w0 = wp[2*dd], w1 = wp[2*dd + 1];
      float s00 = fdot2f(bc_h2(w0.x), ua0[0], fdot2f(bc_h2(w0.y), ua0[1],
                  fdot2f(bc_h2(w0.z), ua0[2], fdot2f(bc_h2(w0.w), ua0[3], 0.f))));
      float s01 = fdot2f(bc_h2(w0.x), ua1[0], fdot2f(bc_h2(w0.y), ua1[1],
                  fdot2f(bc_h2(w0.z), ua1[2], fdot2f(bc_h2(w0.w), ua1[3], 0.f))));
      float s10 = fdot2f(bc_h2(w1.x), ua0[0], fdot2f(bc_h2(w1.y), ua0[1],
                  fdot2f(bc_h2(w1.z), ua0[2], fdot2f(bc_h2(w1.w), ua0[3], 0.f))));
      float s11 = fdot2f(bc_h2(w1.x), ua1[0], fdot2f(bc_h2(w1.y), ua1[1],
                  fdot2f(bc_h2(w1.z), ua1[2], fdot2f(bc_h2(w1.w), ua1[3], 0.f))));
      _Float16 f00 = (_Float16)s00, f10 = (_Float16)s10;
      _Float16 f01 = (_Float16)s01, f11 = (_Float16)s11;
      uh16[0][o*16 + 2*dd][ch]     = bc_u16(f00);
      uh16[0][o*16 + 2*dd + 1][ch] = bc_u16(f10);
      uh16[1][o*16 + 2*dd][ch]     = bc_u16(f01);
      uh16[1][o*16 + 2*dd + 1][ch] = bc_u16(f11);
      uhreg[0][o*8 + dd] = (h2){f00, f10};
      uhreg[1][o*8 + dd] = (h2){f01, f11};
    }
  }

  float lg[2][5] = {{0.f,0.f,0.f,0.f,0.f},{0.f,0.f,0.f,0.f,0.f}};

  for (int it = 0; it < 3; ++it) {
    // softmax over o per (b,c) -> coc16 fp16
#pragma unroll
    for (int bb = 0; bb < 2; ++bb) {
      float m = fmaxf(fmaxf(fmaxf(lg[bb][0],lg[bb][1]),fmaxf(lg[bb][2],lg[bb][3])),lg[bb][4]);
      float e[5]; float Z = 0.f;
#pragma unroll
      for (int o = 0; o < 5; ++o) { e[o] = __expf(lg[bb][o]-m); Z += e[o]; }
      float inv = 1.f / Z;
#pragma unroll
      for (int o = 0; o < 5; ++o) {
        _Float16 hc = (_Float16)(e[o]*inv);
        coc16[bb][o][ch] = bc_u16(hc);
      }
    }
    __syncthreads();

    // s-phase: thread (od,qq) dots a 96-c strip for both b (uh from LDS)
    if (t < 320) {
      int od = t >> 2, qq = t & 3, o = od >> 4;
#pragma unroll
      for (int bb = 0; bb < 2; ++bb) {
        const uint4* ua = (const uint4*)&uh16[bb][od][qq*104];
        const uint4* ca = (const uint4*)&coc16[bb][o][qq*104];
        float sum = 0.f;
#pragma unroll
        for (int j = 0; j < 12; ++j) {
          uint4 uv = ua[j];
          uint4 cv = ca[j];
          sum = fdot2f(bc_h2(uv.x), bc_h2(cv.x), sum);
          sum = fdot2f(bc_h2(uv.y), bc_h2(cv.y), sum);
          sum = fdot2f(bc_h2(uv.z), bc_h2(cv.z), sum);
          sum = fdot2f(bc_h2(uv.w), bc_h2(cv.w), sum);
        }
        sum += __shfl_xor(sum, 1);
        sum += __shfl_xor(sum, 2);
        if (qq == 0) sv[bb][od] = sum;
      }
    }
    __syncthreads();

    // squash factor per (b,o); also emit svh16 = fp16(sv*f) for the uv-phase
    if (t < 10) {
      int bb = t / 5, o = t - bb*5;
      float sq = 0.f;
#pragma unroll
      for (int d = 0; d < 16; ++d) { float v = sv[bb][o*16+d]; sq = fmaf(v, v, sq); }
      float f = sq / ((1.f + sq) * (sqrtf(sq) + EPSQ));
      ff[bb][o] = f;
      if (it < 2) {
#pragma unroll
        for (int d = 0; d < 16; ++d) {
          _Float16 hf = (_Float16)(sv[bb][o*16+d] * f);
          svh16[bb][o*16+d] = bc_u16(hf);
        }
      }
    }
    __syncthreads();

    if (it == 2) {
      if (t < 160) {
        int bb = t / 80, od = t - bb*80;
        out[(size_t)(b0+bb)*80 + od] = sv[bb][od] * ff[bb][od >> 4];
      }
    } else {
      // logits update: dv = <tu, v> via packed fdot2 from registers + svh16
#pragma unroll
      for (int bb = 0; bb < 2; ++bb) {
#pragma unroll
        for (int o = 0; o < 5; ++o) {
          uint4 s0 = *(const uint4*)&svh16[bb][o*16];
          uint4 s1 = *(const uint4*)&svh16[bb][o*16 + 8];
          float dv = 0.f;
          dv = fdot2f(uhreg[bb][o*8+0], bc_h2(s0.x), dv);
          dv = fdot2f(uhreg[bb][o*8+1], bc_h2(s0.y), dv);
          dv = fdot2f(uhreg[bb][o*8+2], bc_h2(s0.z), dv);
          dv = fdot2f(uhreg[bb][o*8+3], bc_h2(s0.w), dv);
          dv = fdot2f(uhreg[bb][o*8+4], bc_h2(s1.x), dv);
          dv = fdot2f(uhreg[bb][o*8+5], bc_h2(s1.y), dv);
          dv = fdot2f(uhreg[bb][o*8+6], bc_h2(s1.z), dv);
          dv = fdot2f(uhreg[bb][o*8+7], bc_h2(s1.w), dv);
          lg[bb][o] += dv;
        }
      }
    }
  }
}

extern "C" void kernel_launch(void* const* d_in, const int* in_sizes, int n_in,
                              void* d_out, int out_size, void* d_ws, size_t ws_size,
                              hipStream_t stream) {
  const float* x  = (const float*)d_in[0];
  const float* w1 = (const float*)d_in[1];
  const float* b1 = (const float*)d_in[2];
  const float* pw = (const float*)d_in[3];
  const float* b2 = (const float*)d_in[4];
  const float* Wf = (const float*)d_in[5];
  float* out = (float*)d_out;
  char* ws = (char*)d_ws;

  _Float16* wc16  = (_Float16*)(ws);
  _Float16* pwB16 = (_Float16*)(ws + 147456);
  _Float16* Wh    = (_Float16*)(ws + 167936);
  ushort_t* u16   = (ushort_t*)(ws + 659456);

  k0_prep<<<960, 256, 0, stream>>>(w1, pw, Wf, wc16, pwB16, Wh);
  k12_mfma<<<1366, 256, 0, stream>>>(x, b1, b2, wc16, pwB16, u16);
  k3_route<<<2048, 384, 0, stream>>>(u16, Wh, out);
}